// Round 3
// baseline (2329.338 us; speedup 1.0000x reference)
//
#include <hip/hip_runtime.h>
#include <hip/hip_bf16.h>
#include <math.h>

typedef __hip_bfloat16 bf16;
typedef __bf16 bf16x8 __attribute__((ext_vector_type(8)));
typedef float f32x4 __attribute__((ext_vector_type(4)));

__device__ __forceinline__ float b2f(bf16 v) { return __bfloat162float(v); }
__device__ __forceinline__ bf16 f2b(float v) { return __float2bfloat16(v); }

// ---------------------------------------------------------------------------
// dtype detection: are the input buffers bf16 or fp32?
// bf16 data: low half of each u32 word is a plausible N(0,1) bf16 (exp~[100,140]).
// fp32 data: low half is mantissa bits -> exp field ~uniform (only ~16% in range).
// ---------------------------------------------------------------------------
__global__ void detect_dtype(const unsigned int* __restrict__ x, int* __restrict__ flag) {
  int cnt = 0;
  for (int i = 0; i < 128; ++i) {
    unsigned int lo = x[i] & 0xFFFFu;
    unsigned int e = (lo >> 7) & 0xFFu;
    if (e >= 100u && e <= 140u) ++cnt;
  }
  *flag = (cnt >= 96) ? 1 : 0;   // 1 = bf16 inputs, 0 = fp32 inputs
}

// generic input -> bf16 convert (dtype per flag)
__global__ void convert_in(const void* __restrict__ src, bf16* __restrict__ dst,
                           int n, const int* __restrict__ flag) {
  int i = blockIdx.x * 256 + threadIdx.x;
  if (i >= n) return;
  dst[i] = (*flag) ? ((const bf16*)src)[i] : f2b(((const float*)src)[i]);
}

// final emit: d_out in the harness's dtype
__global__ void emit_kernel(const float* __restrict__ xf, const int* __restrict__ flag,
                            void* __restrict__ out) {
  int i = blockIdx.x * 256 + threadIdx.x;
  if (*flag) ((bf16*)out)[i] = f2b(xf[i]);
  else       ((float*)out)[i] = xf[i];
}

// ---------------------------------------------------------------------------
// Generic batched GEMM: C = alpha * A @ Bt^T  (+bias +resid), bf16 in, fp32 acc
// ---------------------------------------------------------------------------
__global__ __launch_bounds__(256, 2) void gemm_bt(
    const bf16* __restrict__ A, long long sAb, long long sAh, int lda,
    const bf16* __restrict__ Bt, long long sBb, long long sBh, int ldb,
    float alpha,
    const float* __restrict__ resid,
    const bf16* __restrict__ bias,
    float* __restrict__ outf,
    bf16* __restrict__ outb,
    long long sCb, long long sCh, int ldc,
    int M, int N, int K)
{
  __shared__ __bf16 lA[128 * 64] __attribute__((aligned(16)));
  __shared__ __bf16 lB[128 * 64] __attribute__((aligned(16)));

  int z = blockIdx.z, zb = z >> 4, zh = z & 15;
  A  += (long long)zb * sAb + (long long)zh * sAh;
  Bt += (long long)zb * sBb + (long long)zh * sBh;
  long long coff = (long long)zb * sCb + (long long)zh * sCh;

  int tid = threadIdx.x;
  int lane = tid & 63;
  int wave = tid >> 6;
  int quad = lane >> 4, l16 = lane & 15;
  int wm = (wave >> 1) * 64, wn = (wave & 1) * 64;
  int row0 = blockIdx.y * 128, col0 = blockIdx.x * 128;

  f32x4 acc[4][4];
#pragma unroll
  for (int a = 0; a < 4; ++a)
#pragma unroll
    for (int b = 0; b < 4; ++b) acc[a][b] = (f32x4){0.f, 0.f, 0.f, 0.f};

  for (int k0 = 0; k0 < K; k0 += 64) {
    uint4 ra[4], rb[4];
#pragma unroll
    for (int it = 0; it < 4; ++it) {
      int c = it * 256 + tid;
      int r = c >> 3, cc = (c & 7) * 8;
      ra[it] = *(const uint4*)(A + (long long)(row0 + r) * lda + (k0 + cc));
    }
#pragma unroll
    for (int it = 0; it < 4; ++it) {
      int c = it * 256 + tid;
      int r = c >> 3, cc = (c & 7) * 8;
      int n = col0 + r; n = (n < N) ? n : (N - 1);
      rb[it] = *(const uint4*)(Bt + (long long)n * ldb + (k0 + cc));
    }
    __syncthreads();
#pragma unroll
    for (int it = 0; it < 4; ++it) {
      int c = it * 256 + tid;
      *(uint4*)&lA[c * 8] = ra[it];
      *(uint4*)&lB[c * 8] = rb[it];
    }
    __syncthreads();
#pragma unroll
    for (int ks = 0; ks < 2; ++ks) {
      int kb = ks * 32;
      bf16x8 af[4], bfr[4];
#pragma unroll
      for (int mi = 0; mi < 4; ++mi)
        af[mi] = *(const bf16x8*)&lA[(wm + mi * 16 + l16) * 64 + kb + quad * 8];
#pragma unroll
      for (int ni = 0; ni < 4; ++ni)
        bfr[ni] = *(const bf16x8*)&lB[(wn + ni * 16 + l16) * 64 + kb + quad * 8];
#pragma unroll
      for (int mi = 0; mi < 4; ++mi)
#pragma unroll
        for (int ni = 0; ni < 4; ++ni)
          acc[mi][ni] = __builtin_amdgcn_mfma_f32_16x16x32_bf16(
              af[mi], bfr[ni], acc[mi][ni], 0, 0, 0);
    }
  }

#pragma unroll
  for (int mi = 0; mi < 4; ++mi) {
#pragma unroll
    for (int ni = 0; ni < 4; ++ni) {
      int n = col0 + wn + ni * 16 + l16;
      if (n >= N) continue;
#pragma unroll
      for (int r = 0; r < 4; ++r) {
        int m = row0 + wm + mi * 16 + quad * 4 + r;
        float v = acc[mi][ni][r] * alpha;
        long long ci = coff + (long long)m * ldc + n;
        if (bias)  v += b2f(bias[n]);
        if (resid) v += resid[ci];
        if (outf)  outf[ci] = v;
        if (outb)  outb[ci] = f2b(v);
      }
    }
  }
}

// ---------------------------------------------------------------------------
// Elementwise / helper kernels
// ---------------------------------------------------------------------------
__global__ void init_x_kernel(const void* __restrict__ x, const int* __restrict__ flag,
                              float* __restrict__ xf, bf16* __restrict__ xbf) {
  int i = blockIdx.x * 256 + threadIdx.x;
  float v = (*flag) ? b2f(((const bf16*)x)[i]) : ((const float*)x)[i];
  xf[i] = v;
  xbf[i] = f2b(v);
}

// weights transpose: in [R][C] -> out [C][R], batched over blockIdx.z (layers)
__global__ void transpose_w(const void* __restrict__ in, bf16* __restrict__ out,
                            int R, int C, const int* __restrict__ flag) {
  __shared__ bf16 tile[32][33];
  long long zoff = (long long)blockIdx.z * R * C;
  const bf16* inb = (const bf16*)in + zoff;
  const float* inf = (const float*)in + zoff;
  out += zoff;
  int tx = threadIdx.x, ty = threadIdx.y;
  int c0 = blockIdx.x * 32, r0 = blockIdx.y * 32;
  int isb = *flag;
#pragma unroll
  for (int i = 0; i < 4; ++i) {
    long long off = (long long)(r0 + ty + i * 8) * C + (c0 + tx);
    tile[ty + i * 8][tx] = isb ? inb[off] : f2b(inf[off]);
  }
  __syncthreads();
#pragma unroll
  for (int i = 0; i < 4; ++i)
    out[(long long)(c0 + ty + i * 8) * R + (r0 + tx)] = tile[tx][ty + i * 8];
}

// v [b, j, h*64+d] -> vT [(b*16+h)*64+d][1088]
__global__ void transpose_v(const bf16* __restrict__ v, bf16* __restrict__ vT) {
  __shared__ bf16 tile[32][33];
  int z = blockIdx.z, b = z >> 4, h = z & 15;
  const bf16* in = v + (long long)b * 1088 * 1024 + h * 64;
  bf16* out = vT + (long long)z * 64 * 1088;
  int tx = threadIdx.x, ty = threadIdx.y;
  int j0 = blockIdx.x * 32, d0 = blockIdx.y * 32;
#pragma unroll
  for (int i = 0; i < 4; ++i)
    tile[ty + i * 8][tx] = in[(long long)(j0 + ty + i * 8) * 1024 + (d0 + tx)];
  __syncthreads();
#pragma unroll
  for (int i = 0; i < 4; ++i)
    out[(long long)(d0 + ty + i * 8) * 1088 + (j0 + tx)] = tile[tx][ty + i * 8];
}

// rotary on q: q[row(b*256+n)][h*64+d], freqs src_freq[n][d]
__global__ void rotary_q_kernel(bf16* __restrict__ q, const bf16* __restrict__ srcf) {
  int idx = blockIdx.x * 256 + threadIdx.x;   // [0, 2048*512)
  int row = idx >> 9;
  int p = idx & 511;
  int h = p >> 5, i = p & 31;
  int d0 = h * 64 + 2 * i;
  int ntok = row & 255;
  float f = b2f(srcf[ntok * 64 + 2 * i]);
  float c = cosf(f), s = sinf(f);
  long long base = (long long)row * 1024 + d0;
  float q0 = b2f(q[base]), q1 = b2f(q[base + 1]);
  q[base]     = f2b(q0 * c - q1 * s);
  q[base + 1] = f2b(q1 * c + q0 * s);
}

// bias + rotary on memory keys (j < 1024)
__global__ void k_bias_rot_kernel(bf16* __restrict__ k, const bf16* __restrict__ tgtf,
                                  const bf16* __restrict__ rpe,
                                  const int* __restrict__ ridx, int layer) {
  int idx = blockIdx.x * 256 + threadIdx.x;   // [0, 8*1024*512)
  int b = idx >> 19;
  int rem = idx & ((1 << 19) - 1);
  int j = rem >> 9;
  int p = rem & 511;
  int h = p >> 5, i = p & 31;
  int d0 = h * 64 + 2 * i;
  float bias = b2f(rpe[(layer * 405 + ridx[j >> 8]) * 16 + h]);
  float f = b2f(tgtf[j * 64 + 2 * i]);
  float c = cosf(f), s = sinf(f);
  long long base = (long long)(b * 1088 + j) * 1024 + d0;
  float k0 = b2f(k[base]) + bias, k1 = b2f(k[base + 1]) + bias;
  k[base]     = f2b(k0 * c - k1 * s);
  k[base + 1] = f2b(k1 * c + k0 * s);
}

// in-place row softmax over 1088 cols, 1 block per row
__global__ __launch_bounds__(256) void softmax_kernel(bf16* __restrict__ SP) {
  long long row = blockIdx.x;
  bf16* p = SP + row * 1088;
  int tid = threadIdx.x;
  __shared__ float red[256];
  float v[5];
#pragma unroll
  for (int i = 0; i < 5; ++i) {
    int idx = i * 256 + tid;
    v[i] = (idx < 1088) ? b2f(p[idx]) : -1e30f;
  }
  float m = v[0];
#pragma unroll
  for (int i = 1; i < 5; ++i) m = fmaxf(m, v[i]);
  red[tid] = m; __syncthreads();
  for (int s = 128; s > 0; s >>= 1) {
    if (tid < s) red[tid] = fmaxf(red[tid], red[tid + s]);
    __syncthreads();
  }
  m = red[0]; __syncthreads();
  float e[5], sum = 0.f;
#pragma unroll
  for (int i = 0; i < 5; ++i) {
    int idx = i * 256 + tid;
    e[i] = (idx < 1088) ? expf(v[i] - m) : 0.f;
    sum += e[i];
  }
  red[tid] = sum; __syncthreads();
  for (int s = 128; s > 0; s >>= 1) {
    if (tid < s) red[tid] += red[tid + s];
    __syncthreads();
  }
  float inv = 1.0f / red[0];
#pragma unroll
  for (int i = 0; i < 5; ++i) {
    int idx = i * 256 + tid;
    if (idx < 1088) p[idx] = f2b(e[i] * inv);
  }
}

// GEGLU
__global__ void geglu_kernel(const bf16* __restrict__ hgl, bf16* __restrict__ y) {
  int idx = blockIdx.x * 256 + threadIdx.x;   // [0, 2048*4096)
  int m = idx >> 12, n = idx & 4095;
  float a = b2f(hgl[(long long)m * 8192 + n]);
  float g = b2f(hgl[(long long)m * 8192 + 4096 + n]);
  float ge = 0.5f * g * (1.0f + erff(g * 0.70710678118654752f));
  y[idx] = f2b(a * ge);
}

// ---------------------------------------------------------------------------
static void launch_gemm(hipStream_t st,
    const bf16* A, long long sAb, long long sAh, int lda,
    const bf16* Bt, long long sBb, long long sBh, int ldb,
    float alpha, const float* resid, const bf16* bias,
    float* outf, bf16* outb, long long sCb, long long sCh, int ldc,
    int M, int N, int K, int batches)
{
  dim3 grid((N + 127) / 128, M / 128, batches);
  gemm_bt<<<grid, dim3(256), 0, st>>>(A, sAb, sAh, lda, Bt, sBb, sBh, ldb, alpha,
                                      resid, bias, outf, outb, sCb, sCh, ldc, M, N, K);
}

extern "C" void kernel_launch(void* const* d_in, const int* in_sizes, int n_in,
                              void* d_out, int out_size, void* d_ws, size_t ws_size,
                              hipStream_t stream) {
  (void)in_sizes; (void)n_in; (void)out_size; (void)ws_size;
  const void* x    = d_in[0];
  const void* cond = d_in[1];
  const void* Wq   = d_in[2];
  const void* Wk   = d_in[3];
  const void* Wv   = d_in[4];
  const void* Wo   = d_in[5];
  const void* bo   = d_in[6];
  const void* rpe  = d_in[7];
  const void* W1   = d_in[8];
  const void* b1   = d_in[9];
  const void* W2   = d_in[10];
  const void* b2   = d_in[11];
  const void* srcf = d_in[12];
  const void* tgtf = d_in[13];
  const int*  ridx = (const int*)d_in[14];

  char* w = (char*)d_ws;
  int* flag = (int*)w;   w += 256;
  bf16* WqT = (bf16*)w;  w += (size_t)2 * 1024 * 1024 * 2;
  bf16* WkT = (bf16*)w;  w += (size_t)2 * 1024 * 1024 * 2;
  bf16* WvT = (bf16*)w;  w += (size_t)2 * 1024 * 1024 * 2;
  bf16* WoT = (bf16*)w;  w += (size_t)2 * 1024 * 1024 * 2;
  bf16* W1T = (bf16*)w;  w += (size_t)2 * 8192 * 1024 * 2;
  bf16* W2T = (bf16*)w;  w += (size_t)2 * 4096 * 1024 * 2;
  bf16* condb = (bf16*)w; w += (size_t)8704 * 1024 * 2;
  bf16* bo_b = (bf16*)w;  w += 2048 * 2;
  bf16* rpe_b = (bf16*)w; w += 12960 * 2;
  bf16* b1_b = (bf16*)w;  w += 16384 * 2;
  bf16* b2_b = (bf16*)w;  w += 2048 * 2;
  bf16* srcf_b = (bf16*)w; w += 16384 * 2;
  bf16* tgtf_b = (bf16*)w; w += 65536 * 2;
  float* xf = (float*)w; w += (size_t)2048 * 1024 * 4;
  bf16* xbf = (bf16*)w;  w += (size_t)2048 * 1024 * 2;
  bf16* qbuf = (bf16*)w; w += (size_t)2048 * 1024 * 2;
  bf16* kbuf = (bf16*)w; w += (size_t)8704 * 1024 * 2;
  bf16* vT  = (bf16*)w;  w += (size_t)128 * 64 * 1088 * 2;
  bf16* att = (bf16*)w;  w += (size_t)2048 * 1024 * 2;
  bf16* SP  = (bf16*)w;  w += (size_t)128 * 256 * 1088 * 2;   // 68 MiB
  // aliases into SP region (lifetimes disjoint from the score matrix):
  bf16* vbuf = SP;                                            // 17 MiB (dead before S-GEMM)
  bf16* hgl  = SP;                                            // 32 MiB (FF phase)
  bf16* ybuf = (bf16*)((char*)SP + (size_t)2048 * 8192 * 2);  // 16 MiB (FF phase)

  detect_dtype<<<1, 1, 0, stream>>>((const unsigned int*)x, flag);

  convert_in<<<34816, 256, 0, stream>>>(cond, condb, 8704 * 1024, flag);
  convert_in<<<8, 256, 0, stream>>>(bo, bo_b, 2048, flag);
  convert_in<<<51, 256, 0, stream>>>(rpe, rpe_b, 12960, flag);
  convert_in<<<64, 256, 0, stream>>>(b1, b1_b, 16384, flag);
  convert_in<<<8, 256, 0, stream>>>(b2, b2_b, 2048, flag);
  convert_in<<<64, 256, 0, stream>>>(srcf, srcf_b, 16384, flag);
  convert_in<<<256, 256, 0, stream>>>(tgtf, tgtf_b, 65536, flag);

  dim3 tb(32, 8);
  transpose_w<<<dim3(32, 32, 2),  tb, 0, stream>>>(Wq, WqT, 1024, 1024, flag);
  transpose_w<<<dim3(32, 32, 2),  tb, 0, stream>>>(Wk, WkT, 1024, 1024, flag);
  transpose_w<<<dim3(32, 32, 2),  tb, 0, stream>>>(Wv, WvT, 1024, 1024, flag);
  transpose_w<<<dim3(32, 32, 2),  tb, 0, stream>>>(Wo, WoT, 1024, 1024, flag);
  transpose_w<<<dim3(256, 32, 2), tb, 0, stream>>>(W1, W1T, 1024, 8192, flag);
  transpose_w<<<dim3(32, 128, 2), tb, 0, stream>>>(W2, W2T, 4096, 1024, flag);
  init_x_kernel<<<8192, 256, 0, stream>>>(x, flag, xf, xbf);

  for (int l = 0; l < 2; ++l) {
    const bf16* WqTl = WqT + (size_t)l * 1024 * 1024;
    const bf16* WkTl = WkT + (size_t)l * 1024 * 1024;
    const bf16* WvTl = WvT + (size_t)l * 1024 * 1024;
    const bf16* WoTl = WoT + (size_t)l * 1024 * 1024;
    const bf16* W1Tl = W1T + (size_t)l * 8192 * 1024;
    const bf16* W2Tl = W2T + (size_t)l * 4096 * 1024;

    // q = x @ Wq ; rotary
    launch_gemm(stream, xbf, 0, 0, 1024, WqTl, 0, 0, 1024, 1.f,
                nullptr, nullptr, nullptr, qbuf, 0, 0, 1024, 2048, 1024, 1024, 1);
    rotary_q_kernel<<<4096, 256, 0, stream>>>(qbuf, srcf_b);
    // v = cond @ Wv ; transpose per (b,h)   (vbuf aliases SP -> do before S)
    launch_gemm(stream, condb, 0, 0, 1024, WvTl, 0, 0, 1024, 1.f,
                nullptr, nullptr, nullptr, vbuf, 0, 0, 1024, 8704, 1024, 1024, 1);
    transpose_v<<<dim3(34, 2, 128), tb, 0, stream>>>(vbuf, vT);
    // k = cond @ Wk ; bias + rotary on memory part
    launch_gemm(stream, condb, 0, 0, 1024, WkTl, 0, 0, 1024, 1.f,
                nullptr, nullptr, nullptr, kbuf, 0, 0, 1024, 8704, 1024, 1024, 1);
    k_bias_rot_kernel<<<16384, 256, 0, stream>>>(kbuf, tgtf_b, rpe_b, ridx, l);
    // S = scale * q @ k^T   (batched over 128 (b,h))
    launch_gemm(stream, qbuf, 262144, 64, 1024, kbuf, 1114112, 64, 1024, 0.125f,
                nullptr, nullptr, nullptr, SP, 4456448, 278528, 1088, 256, 1088, 64, 128);
    softmax_kernel<<<32768, 256, 0, stream>>>(SP);
    // O = P @ V
    launch_gemm(stream, SP, 4456448, 278528, 1088, vT, 1114112, 69632, 1088, 1.f,
                nullptr, nullptr, nullptr, att, 262144, 64, 1024, 256, 64, 1088, 128);
    // x = x + O @ Wo + bo
    launch_gemm(stream, att, 0, 0, 1024, WoTl, 0, 0, 1024, 1.f,
                xf, bo_b + (size_t)l * 1024, xf, xbf, 0, 0, 1024, 2048, 1024, 1024, 1);
    // FF1: hgl = x @ W1 + b1
    launch_gemm(stream, xbf, 0, 0, 1024, W1Tl, 0, 0, 1024, 1.f,
                nullptr, b1_b + (size_t)l * 8192, nullptr, hgl, 0, 0, 8192, 2048, 8192, 1024, 1);
    geglu_kernel<<<32768, 256, 0, stream>>>(hgl, ybuf);
    // FF2: x = x + y @ W2 + b2
    launch_gemm(stream, ybuf, 0, 0, 4096, W2Tl, 0, 0, 4096, 1.f,
                xf, b2_b + (size_t)l * 1024, xf, xbf, 0, 0, 1024, 2048, 1024, 4096, 1);
  }

  emit_kernel<<<8192, 256, 0, stream>>>(xf, flag, d_out);
}

// Round 4
// 2264.218 us; speedup vs baseline: 1.0288x; 1.0288x over previous
//
#include <hip/hip_runtime.h>
#include <hip/hip_bf16.h>
#include <math.h>

typedef __hip_bfloat16 bf16;
typedef __bf16 bf16x8 __attribute__((ext_vector_type(8)));
typedef float f32x4 __attribute__((ext_vector_type(4)));

__device__ __forceinline__ float b2f(bf16 v) { return __bfloat162float(v); }
__device__ __forceinline__ bf16 f2b(float v) { return __float2bfloat16(v); }

__device__ __forceinline__ f32x4 shfl_xor4(f32x4 v, int m) {
  f32x4 o;
  o[0] = __shfl_xor(v[0], m);
  o[1] = __shfl_xor(v[1], m);
  o[2] = __shfl_xor(v[2], m);
  o[3] = __shfl_xor(v[3], m);
  return o;
}
__device__ __forceinline__ f32x4 max4(f32x4 a, f32x4 b) {
  f32x4 o;
  o[0] = fmaxf(a[0], b[0]); o[1] = fmaxf(a[1], b[1]);
  o[2] = fmaxf(a[2], b[2]); o[3] = fmaxf(a[3], b[3]);
  return o;
}
__device__ __forceinline__ f32x4 exp4(f32x4 a) {
  f32x4 o;
  o[0] = __expf(a[0]); o[1] = __expf(a[1]);
  o[2] = __expf(a[2]); o[3] = __expf(a[3]);
  return o;
}

// ---------------------------------------------------------------------------
// dtype detection (inputs bf16 vs fp32), device-side, deterministic per call
// ---------------------------------------------------------------------------
__global__ void detect_dtype(const unsigned int* __restrict__ x, int* __restrict__ flag) {
  int cnt = 0;
  for (int i = 0; i < 128; ++i) {
    unsigned int lo = x[i] & 0xFFFFu;
    unsigned int e = (lo >> 7) & 0xFFu;
    if (e >= 100u && e <= 140u) ++cnt;
  }
  *flag = (cnt >= 96) ? 1 : 0;
}

__global__ void convert_in(const void* __restrict__ src, bf16* __restrict__ dst,
                           int n, const int* __restrict__ flag) {
  int i = blockIdx.x * 256 + threadIdx.x;
  if (i >= n) return;
  dst[i] = (*flag) ? ((const bf16*)src)[i] : f2b(((const float*)src)[i]);
}

__global__ void emit_kernel(const float* __restrict__ xf, const int* __restrict__ flag,
                            void* __restrict__ out) {
  int i = blockIdx.x * 256 + threadIdx.x;
  if (*flag) ((bf16*)out)[i] = f2b(xf[i]);
  else       ((float*)out)[i] = xf[i];
}

// ---------------------------------------------------------------------------
// Generic GEMM: C = alpha * A @ Bt^T (+bias +resid), bf16 in, fp32 acc
// ---------------------------------------------------------------------------
__global__ __launch_bounds__(256, 2) void gemm_bt(
    const bf16* __restrict__ A, long long sAb, long long sAh, int lda,
    const bf16* __restrict__ Bt, long long sBb, long long sBh, int ldb,
    float alpha,
    const float* __restrict__ resid,
    const bf16* __restrict__ bias,
    float* __restrict__ outf,
    bf16* __restrict__ outb,
    long long sCb, long long sCh, int ldc,
    int M, int N, int K)
{
  __shared__ __bf16 lA[128 * 64] __attribute__((aligned(16)));
  __shared__ __bf16 lB[128 * 64] __attribute__((aligned(16)));

  int z = blockIdx.z, zb = z >> 4, zh = z & 15;
  A  += (long long)zb * sAb + (long long)zh * sAh;
  Bt += (long long)zb * sBb + (long long)zh * sBh;
  long long coff = (long long)zb * sCb + (long long)zh * sCh;

  int tid = threadIdx.x;
  int lane = tid & 63;
  int wave = tid >> 6;
  int quad = lane >> 4, l16 = lane & 15;
  int wm = (wave >> 1) * 64, wn = (wave & 1) * 64;
  int row0 = blockIdx.y * 128, col0 = blockIdx.x * 128;

  f32x4 acc[4][4];
#pragma unroll
  for (int a = 0; a < 4; ++a)
#pragma unroll
    for (int b = 0; b < 4; ++b) acc[a][b] = (f32x4){0.f, 0.f, 0.f, 0.f};

  for (int k0 = 0; k0 < K; k0 += 64) {
    uint4 ra[4], rb[4];
#pragma unroll
    for (int it = 0; it < 4; ++it) {
      int c = it * 256 + tid;
      int r = c >> 3, cc = (c & 7) * 8;
      ra[it] = *(const uint4*)(A + (long long)(row0 + r) * lda + (k0 + cc));
    }
#pragma unroll
    for (int it = 0; it < 4; ++it) {
      int c = it * 256 + tid;
      int r = c >> 3, cc = (c & 7) * 8;
      int n = col0 + r; n = (n < N) ? n : (N - 1);
      rb[it] = *(const uint4*)(Bt + (long long)n * ldb + (k0 + cc));
    }
    __syncthreads();
#pragma unroll
    for (int it = 0; it < 4; ++it) {
      int c = it * 256 + tid;
      *(uint4*)&lA[c * 8] = ra[it];
      *(uint4*)&lB[c * 8] = rb[it];
    }
    __syncthreads();
#pragma unroll
    for (int ks = 0; ks < 2; ++ks) {
      int kb = ks * 32;
      bf16x8 af[4], bfr[4];
#pragma unroll
      for (int mi = 0; mi < 4; ++mi)
        af[mi] = *(const bf16x8*)&lA[(wm + mi * 16 + l16) * 64 + kb + quad * 8];
#pragma unroll
      for (int ni = 0; ni < 4; ++ni)
        bfr[ni] = *(const bf16x8*)&lB[(wn + ni * 16 + l16) * 64 + kb + quad * 8];
#pragma unroll
      for (int mi = 0; mi < 4; ++mi)
#pragma unroll
        for (int ni = 0; ni < 4; ++ni)
          acc[mi][ni] = __builtin_amdgcn_mfma_f32_16x16x32_bf16(
              af[mi], bfr[ni], acc[mi][ni], 0, 0, 0);
    }
  }

#pragma unroll
  for (int mi = 0; mi < 4; ++mi) {
#pragma unroll
    for (int ni = 0; ni < 4; ++ni) {
      int n = col0 + wn + ni * 16 + l16;
      if (n >= N) continue;
#pragma unroll
      for (int r = 0; r < 4; ++r) {
        int m = row0 + wm + mi * 16 + quad * 4 + r;
        float v = acc[mi][ni][r] * alpha;
        long long ci = coff + (long long)m * ldc + n;
        if (bias)  v += b2f(bias[n]);
        if (resid) v += resid[ci];
        if (outf)  outf[ci] = v;
        if (outb)  outb[ci] = f2b(v);
      }
    }
  }
}

// ---------------------------------------------------------------------------
// Fused flash attention: one WG per (b, h, q-half), 4 waves, 32 q-rows/wave.
// q [2048][1024], k [8704][1024] (bias+rotary applied), vt [(b*16+h)*64+d][1088]
// att [2048][1024].  S = (q k^T)/8, online softmax, O = P V.
// ---------------------------------------------------------------------------
__global__ __launch_bounds__(256, 2) void flash_attn(
    const bf16* __restrict__ q, const bf16* __restrict__ k,
    const bf16* __restrict__ vt, bf16* __restrict__ att)
{
  __shared__ __bf16 lK[128 * 72] __attribute__((aligned(16)));   // [key][d] pad 8
  __shared__ __bf16 lV[64 * 136] __attribute__((aligned(16)));   // [d][key] pad 8
  __shared__ __bf16 lP[4][32 * 40] __attribute__((aligned(16))); // per-wave P chunk

  int idx = blockIdx.x;                 // 0..255
  int b = idx >> 5, h = (idx >> 1) & 15, half = idx & 1;
  int tid = threadIdx.x, wave = tid >> 6, lane = tid & 63;
  int quad = lane >> 4, l16 = lane & 15;
  int qrow0 = b * 256 + half * 128 + wave * 32;

  const bf16* kb  = k  + (long long)b * 1088 * 1024 + h * 64;
  const bf16* vtb = vt + (long long)(b * 16 + h) * 64 * 1088;
  bf16* lPw = (bf16*)&lP[wave][0];

  // Q fragments held in registers: A[m=l16][k=quad*8+j], 2 m-tiles x 2 k-steps
  bf16x8 qa[2][2];
#pragma unroll
  for (int mi = 0; mi < 2; ++mi)
#pragma unroll
    for (int ks = 0; ks < 2; ++ks)
      qa[mi][ks] = *(const bf16x8*)&q[(long long)(qrow0 + mi * 16 + l16) * 1024 +
                                      h * 64 + ks * 32 + quad * 8];

  f32x4 accO[2][4];
  f32x4 mrow[2], lrow[2];
#pragma unroll
  for (int mi = 0; mi < 2; ++mi) {
    mrow[mi] = (f32x4){-INFINITY, -INFINITY, -INFINITY, -INFINITY};
    lrow[mi] = (f32x4){0.f, 0.f, 0.f, 0.f};
#pragma unroll
    for (int nd = 0; nd < 4; ++nd) accO[mi][nd] = (f32x4){0.f, 0.f, 0.f, 0.f};
  }

  for (int j0 = 0; j0 < 1088; j0 += 128) {
    int tk = 1088 - j0; tk = (tk < 128) ? tk : 128;
    __syncthreads();
#pragma unroll
    for (int i = 0; i < 4; ++i) {          // K-tile [tk][64]
      int t = i * 256 + tid;
      int r = t >> 3, c = (t & 7) * 8;
      if (r < tk)
        *(uint4*)&lK[r * 72 + c] = *(const uint4*)&kb[(long long)(j0 + r) * 1024 + c];
    }
#pragma unroll
    for (int i = 0; i < 4; ++i) {          // V^T-tile [64][tk]
      int t = i * 256 + tid;
      int d = t >> 4, c = (t & 15) * 8;
      if (c < tk)
        *(uint4*)&lV[d * 136 + c] = *(const uint4*)&vtb[(long long)d * 1088 + j0 + c];
    }
    __syncthreads();

    int ntiles = tk >> 4;                  // 8 or 4
    f32x4 accS[2][8];
#pragma unroll
    for (int mi = 0; mi < 2; ++mi)
#pragma unroll
      for (int ni = 0; ni < 8; ++ni) accS[mi][ni] = (f32x4){0.f, 0.f, 0.f, 0.f};

    for (int ni = 0; ni < ntiles; ++ni) {
#pragma unroll
      for (int ks = 0; ks < 2; ++ks) {
        bf16x8 bfr = *(const bf16x8*)&lK[(ni * 16 + l16) * 72 + ks * 32 + quad * 8];
        accS[0][ni] = __builtin_amdgcn_mfma_f32_16x16x32_bf16(qa[0][ks], bfr, accS[0][ni], 0, 0, 0);
        accS[1][ni] = __builtin_amdgcn_mfma_f32_16x16x32_bf16(qa[1][ks], bfr, accS[1][ni], 0, 0, 0);
      }
    }

    // online softmax update (per-row state in components r of f32x4)
#pragma unroll
    for (int mi = 0; mi < 2; ++mi) {
      f32x4 vmax = (f32x4){-INFINITY, -INFINITY, -INFINITY, -INFINITY};
      for (int ni = 0; ni < ntiles; ++ni) {
        accS[mi][ni] *= 0.125f;
        vmax = max4(vmax, accS[mi][ni]);
      }
#pragma unroll
      for (int m = 1; m <= 8; m <<= 1) vmax = max4(vmax, shfl_xor4(vmax, m));
      f32x4 mnew = max4(mrow[mi], vmax);
      f32x4 alpha = exp4(mrow[mi] - mnew);
      f32x4 rs = (f32x4){0.f, 0.f, 0.f, 0.f};
      for (int ni = 0; ni < ntiles; ++ni) {
        accS[mi][ni] = exp4(accS[mi][ni] - mnew);
        rs += accS[mi][ni];
      }
#pragma unroll
      for (int m = 1; m <= 8; m <<= 1) rs += shfl_xor4(rs, m);
      lrow[mi] = lrow[mi] * alpha + rs;
      mrow[mi] = mnew;
#pragma unroll
      for (int nd = 0; nd < 4; ++nd) accO[mi][nd] *= alpha;
    }

    // P @ V in 32-key chunks through per-wave LDS (C-layout -> A-layout)
    int nch = tk >> 5;                     // 4 or 2
    for (int c = 0; c < nch; ++c) {
#pragma unroll
      for (int mi = 0; mi < 2; ++mi)
#pragma unroll
        for (int u = 0; u < 2; ++u) {
          int ni = c * 2 + u;
#pragma unroll
          for (int r = 0; r < 4; ++r)
            lPw[(mi * 16 + quad * 4 + r) * 40 + u * 16 + l16] = f2b(accS[mi][ni][r]);
        }
      bf16x8 pa[2];
      pa[0] = *(const bf16x8*)&lPw[(l16) * 40 + quad * 8];
      pa[1] = *(const bf16x8*)&lPw[(16 + l16) * 40 + quad * 8];
#pragma unroll
      for (int nd = 0; nd < 4; ++nd) {
        bf16x8 vb = *(const bf16x8*)&lV[(nd * 16 + l16) * 136 + c * 32 + quad * 8];
        accO[0][nd] = __builtin_amdgcn_mfma_f32_16x16x32_bf16(pa[0], vb, accO[0][nd], 0, 0, 0);
        accO[1][nd] = __builtin_amdgcn_mfma_f32_16x16x32_bf16(pa[1], vb, accO[1][nd], 0, 0, 0);
      }
    }
  }

  // normalize and store
#pragma unroll
  for (int mi = 0; mi < 2; ++mi) {
    f32x4 inv;
    inv[0] = 1.f / lrow[mi][0]; inv[1] = 1.f / lrow[mi][1];
    inv[2] = 1.f / lrow[mi][2]; inv[3] = 1.f / lrow[mi][3];
#pragma unroll
    for (int nd = 0; nd < 4; ++nd) {
      f32x4 o = accO[mi][nd] * inv;
#pragma unroll
      for (int r = 0; r < 4; ++r)
        att[(long long)(qrow0 + mi * 16 + quad * 4 + r) * 1024 +
            h * 64 + nd * 16 + l16] = f2b(o[r]);
    }
  }
}

// ---------------------------------------------------------------------------
// Elementwise / helper kernels
// ---------------------------------------------------------------------------
__global__ void init_x_kernel(const void* __restrict__ x, const int* __restrict__ flag,
                              float* __restrict__ xf, bf16* __restrict__ xbf) {
  int i = blockIdx.x * 256 + threadIdx.x;
  float v = (*flag) ? b2f(((const bf16*)x)[i]) : ((const float*)x)[i];
  xf[i] = v;
  xbf[i] = f2b(v);
}

__global__ void transpose_w(const void* __restrict__ in, bf16* __restrict__ out,
                            int R, int C, const int* __restrict__ flag) {
  __shared__ bf16 tile[32][33];
  long long zoff = (long long)blockIdx.z * R * C;
  const bf16* inb = (const bf16*)in + zoff;
  const float* inf = (const float*)in + zoff;
  out += zoff;
  int tx = threadIdx.x, ty = threadIdx.y;
  int c0 = blockIdx.x * 32, r0 = blockIdx.y * 32;
  int isb = *flag;
#pragma unroll
  for (int i = 0; i < 4; ++i) {
    long long off = (long long)(r0 + ty + i * 8) * C + (c0 + tx);
    tile[ty + i * 8][tx] = isb ? inb[off] : f2b(inf[off]);
  }
  __syncthreads();
#pragma unroll
  for (int i = 0; i < 4; ++i)
    out[(long long)(c0 + ty + i * 8) * R + (r0 + tx)] = tile[tx][ty + i * 8];
}

__global__ void transpose_v(const bf16* __restrict__ v, bf16* __restrict__ vT) {
  __shared__ bf16 tile[32][33];
  int z = blockIdx.z, b = z >> 4, h = z & 15;
  const bf16* in = v + (long long)b * 1088 * 1024 + h * 64;
  bf16* out = vT + (long long)z * 64 * 1088;
  int tx = threadIdx.x, ty = threadIdx.y;
  int j0 = blockIdx.x * 32, d0 = blockIdx.y * 32;
#pragma unroll
  for (int i = 0; i < 4; ++i)
    tile[ty + i * 8][tx] = in[(long long)(j0 + ty + i * 8) * 1024 + (d0 + tx)];
  __syncthreads();
#pragma unroll
  for (int i = 0; i < 4; ++i)
    out[(long long)(d0 + ty + i * 8) * 1088 + (j0 + tx)] = tile[tx][ty + i * 8];
}

__global__ void rotary_q_kernel(bf16* __restrict__ q, const bf16* __restrict__ srcf) {
  int idx = blockIdx.x * 256 + threadIdx.x;
  int row = idx >> 9;
  int p = idx & 511;
  int h = p >> 5, i = p & 31;
  int d0 = h * 64 + 2 * i;
  int ntok = row & 255;
  float f = b2f(srcf[ntok * 64 + 2 * i]);
  float c = cosf(f), s = sinf(f);
  long long base = (long long)row * 1024 + d0;
  float q0 = b2f(q[base]), q1 = b2f(q[base + 1]);
  q[base]     = f2b(q0 * c - q1 * s);
  q[base + 1] = f2b(q1 * c + q0 * s);
}

__global__ void k_bias_rot_kernel(bf16* __restrict__ k, const bf16* __restrict__ tgtf,
                                  const bf16* __restrict__ rpe,
                                  const int* __restrict__ ridx, int layer) {
  int idx = blockIdx.x * 256 + threadIdx.x;
  int b = idx >> 19;
  int rem = idx & ((1 << 19) - 1);
  int j = rem >> 9;
  int p = rem & 511;
  int h = p >> 5, i = p & 31;
  int d0 = h * 64 + 2 * i;
  float bias = b2f(rpe[(layer * 405 + ridx[j >> 8]) * 16 + h]);
  float f = b2f(tgtf[j * 64 + 2 * i]);
  float c = cosf(f), s = sinf(f);
  long long base = (long long)(b * 1088 + j) * 1024 + d0;
  float k0 = b2f(k[base]) + bias, k1 = b2f(k[base + 1]) + bias;
  k[base]     = f2b(k0 * c - k1 * s);
  k[base + 1] = f2b(k1 * c + k0 * s);
}

__global__ void geglu_kernel(const bf16* __restrict__ hgl, bf16* __restrict__ y) {
  int idx = blockIdx.x * 256 + threadIdx.x;
  int m = idx >> 12, n = idx & 4095;
  float a = b2f(hgl[(long long)m * 8192 + n]);
  float g = b2f(hgl[(long long)m * 8192 + 4096 + n]);
  float ge = 0.5f * g * (1.0f + erff(g * 0.70710678118654752f));
  y[idx] = f2b(a * ge);
}

// ---------------------------------------------------------------------------
static void launch_gemm(hipStream_t st,
    const bf16* A, long long sAb, long long sAh, int lda,
    const bf16* Bt, long long sBb, long long sBh, int ldb,
    float alpha, const float* resid, const bf16* bias,
    float* outf, bf16* outb, long long sCb, long long sCh, int ldc,
    int M, int N, int K, int batches)
{
  dim3 grid((N + 127) / 128, M / 128, batches);
  gemm_bt<<<grid, dim3(256), 0, st>>>(A, sAb, sAh, lda, Bt, sBb, sBh, ldb, alpha,
                                      resid, bias, outf, outb, sCb, sCh, ldc, M, N, K);
}

extern "C" void kernel_launch(void* const* d_in, const int* in_sizes, int n_in,
                              void* d_out, int out_size, void* d_ws, size_t ws_size,
                              hipStream_t stream) {
  (void)in_sizes; (void)n_in; (void)out_size; (void)ws_size;
  const void* x    = d_in[0];
  const void* cond = d_in[1];
  const void* Wq   = d_in[2];
  const void* Wk   = d_in[3];
  const void* Wv   = d_in[4];
  const void* Wo   = d_in[5];
  const void* bo   = d_in[6];
  const void* rpe  = d_in[7];
  const void* W1   = d_in[8];
  const void* b1   = d_in[9];
  const void* W2   = d_in[10];
  const void* b2   = d_in[11];
  const void* srcf = d_in[12];
  const void* tgtf = d_in[13];
  const int*  ridx = (const int*)d_in[14];

  char* w = (char*)d_ws;
  int* flag = (int*)w;   w += 256;
  bf16* WqT = (bf16*)w;  w += (size_t)2 * 1024 * 1024 * 2;
  bf16* WkT = (bf16*)w;  w += (size_t)2 * 1024 * 1024 * 2;
  bf16* WvT = (bf16*)w;  w += (size_t)2 * 1024 * 1024 * 2;
  bf16* WoT = (bf16*)w;  w += (size_t)2 * 1024 * 1024 * 2;
  bf16* W1T = (bf16*)w;  w += (size_t)2 * 8192 * 1024 * 2;
  bf16* W2T = (bf16*)w;  w += (size_t)2 * 4096 * 1024 * 2;
  bf16* condb = (bf16*)w; w += (size_t)8704 * 1024 * 2;
  bf16* bo_b = (bf16*)w;  w += 2048 * 2;
  bf16* rpe_b = (bf16*)w; w += 12960 * 2;
  bf16* b1_b = (bf16*)w;  w += 16384 * 2;
  bf16* b2_b = (bf16*)w;  w += 2048 * 2;
  bf16* srcf_b = (bf16*)w; w += 16384 * 2;
  bf16* tgtf_b = (bf16*)w; w += 65536 * 2;
  float* xf = (float*)w; w += (size_t)2048 * 1024 * 4;
  bf16* xbf = (bf16*)w;  w += (size_t)2048 * 1024 * 2;
  bf16* qbuf = (bf16*)w; w += (size_t)2048 * 1024 * 2;
  bf16* kbuf = (bf16*)w; w += (size_t)8704 * 1024 * 2;
  bf16* vT  = (bf16*)w;  w += (size_t)128 * 64 * 1088 * 2;
  bf16* att = (bf16*)w;  w += (size_t)2048 * 1024 * 2;
  bf16* hgl = (bf16*)w;  w += (size_t)2048 * 8192 * 2;   // 32 MiB (FF phase)
  bf16* ybuf = (bf16*)w; w += (size_t)2048 * 4096 * 2;   // 16 MiB
  bf16* vbuf = hgl;  // v projection scratch; dead before FF1 writes hgl

  detect_dtype<<<1, 1, 0, stream>>>((const unsigned int*)x, flag);

  convert_in<<<34816, 256, 0, stream>>>(cond, condb, 8704 * 1024, flag);
  convert_in<<<8, 256, 0, stream>>>(bo, bo_b, 2048, flag);
  convert_in<<<51, 256, 0, stream>>>(rpe, rpe_b, 12960, flag);
  convert_in<<<64, 256, 0, stream>>>(b1, b1_b, 16384, flag);
  convert_in<<<8, 256, 0, stream>>>(b2, b2_b, 2048, flag);
  convert_in<<<64, 256, 0, stream>>>(srcf, srcf_b, 16384, flag);
  convert_in<<<256, 256, 0, stream>>>(tgtf, tgtf_b, 65536, flag);

  dim3 tb(32, 8);
  transpose_w<<<dim3(32, 32, 2),  tb, 0, stream>>>(Wq, WqT, 1024, 1024, flag);
  transpose_w<<<dim3(32, 32, 2),  tb, 0, stream>>>(Wk, WkT, 1024, 1024, flag);
  transpose_w<<<dim3(32, 32, 2),  tb, 0, stream>>>(Wv, WvT, 1024, 1024, flag);
  transpose_w<<<dim3(32, 32, 2),  tb, 0, stream>>>(Wo, WoT, 1024, 1024, flag);
  transpose_w<<<dim3(256, 32, 2), tb, 0, stream>>>(W1, W1T, 1024, 8192, flag);
  transpose_w<<<dim3(32, 128, 2), tb, 0, stream>>>(W2, W2T, 4096, 1024, flag);
  init_x_kernel<<<8192, 256, 0, stream>>>(x, flag, xf, xbf);

  for (int l = 0; l < 2; ++l) {
    const bf16* WqTl = WqT + (size_t)l * 1024 * 1024;
    const bf16* WkTl = WkT + (size_t)l * 1024 * 1024;
    const bf16* WvTl = WvT + (size_t)l * 1024 * 1024;
    const bf16* WoTl = WoT + (size_t)l * 1024 * 1024;
    const bf16* W1Tl = W1T + (size_t)l * 8192 * 1024;
    const bf16* W2Tl = W2T + (size_t)l * 4096 * 1024;

    // q = x @ Wq ; rotary
    launch_gemm(stream, xbf, 0, 0, 1024, WqTl, 0, 0, 1024, 1.f,
                nullptr, nullptr, nullptr, qbuf, 0, 0, 1024, 2048, 1024, 1024, 1);
    rotary_q_kernel<<<4096, 256, 0, stream>>>(qbuf, srcf_b);
    // v = cond @ Wv ; transpose per (b,h)
    launch_gemm(stream, condb, 0, 0, 1024, WvTl, 0, 0, 1024, 1.f,
                nullptr, nullptr, nullptr, vbuf, 0, 0, 1024, 8704, 1024, 1024, 1);
    transpose_v<<<dim3(34, 2, 128), tb, 0, stream>>>(vbuf, vT);
    // k = cond @ Wk ; bias + rotary on memory part
    launch_gemm(stream, condb, 0, 0, 1024, WkTl, 0, 0, 1024, 1.f,
                nullptr, nullptr, nullptr, kbuf, 0, 0, 1024, 8704, 1024, 1024, 1);
    k_bias_rot_kernel<<<16384, 256, 0, stream>>>(kbuf, tgtf_b, rpe_b, ridx, l);
    // fused attention: S -> softmax -> P@V
    flash_attn<<<256, 256, 0, stream>>>(qbuf, kbuf, vT, att);
    // x = x + O @ Wo + bo
    launch_gemm(stream, att, 0, 0, 1024, WoTl, 0, 0, 1024, 1.f,
                xf, bo_b + (size_t)l * 1024, xf, xbf, 0, 0, 1024, 2048, 1024, 1024, 1);
    // FF1: hgl = x @ W1 + b1
    launch_gemm(stream, xbf, 0, 0, 1024, W1Tl, 0, 0, 1024, 1.f,
                nullptr, b1_b + (size_t)l * 8192, nullptr, hgl, 0, 0, 8192, 2048, 8192, 1024, 1);
    geglu_kernel<<<32768, 256, 0, stream>>>(hgl, ybuf);
    // FF2: x = x + y @ W2 + b2
    launch_gemm(stream, ybuf, 0, 0, 4096, W2Tl, 0, 0, 4096, 1.f,
                xf, b2_b + (size_t)l * 1024, xf, xbf, 0, 0, 1024, 2048, 1024, 4096, 1);
  }

  emit_kernel<<<8192, 256, 0, stream>>>(xf, flag, d_out);
}

// Round 5
// 1852.678 us; speedup vs baseline: 1.2573x; 1.2221x over previous
//
#include <hip/hip_runtime.h>
#include <hip/hip_bf16.h>
#include <math.h>

typedef __hip_bfloat16 bf16;
typedef __bf16 bf16x8 __attribute__((ext_vector_type(8)));
typedef float f32x4 __attribute__((ext_vector_type(4)));

__device__ __forceinline__ float b2f(bf16 v) { return __bfloat162float(v); }
__device__ __forceinline__ bf16 f2b(float v) { return __float2bfloat16(v); }

__device__ __forceinline__ f32x4 shfl_xor4(f32x4 v, int m) {
  f32x4 o;
  o[0] = __shfl_xor(v[0], m);
  o[1] = __shfl_xor(v[1], m);
  o[2] = __shfl_xor(v[2], m);
  o[3] = __shfl_xor(v[3], m);
  return o;
}
__device__ __forceinline__ f32x4 max4(f32x4 a, f32x4 b) {
  f32x4 o;
  o[0] = fmaxf(a[0], b[0]); o[1] = fmaxf(a[1], b[1]);
  o[2] = fmaxf(a[2], b[2]); o[3] = fmaxf(a[3], b[3]);
  return o;
}
__device__ __forceinline__ f32x4 exp4(f32x4 a) {
  f32x4 o;
  o[0] = __expf(a[0]); o[1] = __expf(a[1]);
  o[2] = __expf(a[2]); o[3] = __expf(a[3]);
  return o;
}

// ---------------------------------------------------------------------------
// dtype detection (inputs bf16 vs fp32), device-side, deterministic per call
// ---------------------------------------------------------------------------
__global__ void detect_dtype(const unsigned int* __restrict__ x, int* __restrict__ flag) {
  int cnt = 0;
  for (int i = 0; i < 128; ++i) {
    unsigned int lo = x[i] & 0xFFFFu;
    unsigned int e = (lo >> 7) & 0xFFu;
    if (e >= 100u && e <= 140u) ++cnt;
  }
  *flag = (cnt >= 96) ? 1 : 0;
}

__global__ void convert_in(const void* __restrict__ src, bf16* __restrict__ dst,
                           int n, const int* __restrict__ flag) {
  int i = blockIdx.x * 256 + threadIdx.x;
  if (i >= n) return;
  dst[i] = (*flag) ? ((const bf16*)src)[i] : f2b(((const float*)src)[i]);
}

__global__ void emit_kernel(const float* __restrict__ xf, const int* __restrict__ flag,
                            void* __restrict__ out) {
  int i = blockIdx.x * 256 + threadIdx.x;
  if (*flag) ((bf16*)out)[i] = f2b(xf[i]);
  else       ((float*)out)[i] = xf[i];
}

// ---------------------------------------------------------------------------
// Generic GEMM: C = alpha * A @ Bt^T (+bias +resid), bf16 in, fp32 acc
// ---------------------------------------------------------------------------
__global__ __launch_bounds__(256, 2) void gemm_bt(
    const bf16* __restrict__ A, long long sAb, long long sAh, int lda,
    const bf16* __restrict__ Bt, long long sBb, long long sBh, int ldb,
    float alpha,
    const float* __restrict__ resid,
    const bf16* __restrict__ bias,
    float* __restrict__ outf,
    bf16* __restrict__ outb,
    long long sCb, long long sCh, int ldc,
    int M, int N, int K)
{
  __shared__ __bf16 lA[128 * 64] __attribute__((aligned(16)));
  __shared__ __bf16 lB[128 * 64] __attribute__((aligned(16)));

  int z = blockIdx.z, zb = z >> 4, zh = z & 15;
  A  += (long long)zb * sAb + (long long)zh * sAh;
  Bt += (long long)zb * sBb + (long long)zh * sBh;
  long long coff = (long long)zb * sCb + (long long)zh * sCh;

  int tid = threadIdx.x;
  int lane = tid & 63;
  int wave = tid >> 6;
  int quad = lane >> 4, l16 = lane & 15;
  int wm = (wave >> 1) * 64, wn = (wave & 1) * 64;
  int row0 = blockIdx.y * 128, col0 = blockIdx.x * 128;

  f32x4 acc[4][4];
#pragma unroll
  for (int a = 0; a < 4; ++a)
#pragma unroll
    for (int b = 0; b < 4; ++b) acc[a][b] = (f32x4){0.f, 0.f, 0.f, 0.f};

  for (int k0 = 0; k0 < K; k0 += 64) {
    uint4 ra[4], rb[4];
#pragma unroll
    for (int it = 0; it < 4; ++it) {
      int c = it * 256 + tid;
      int r = c >> 3, cc = (c & 7) * 8;
      ra[it] = *(const uint4*)(A + (long long)(row0 + r) * lda + (k0 + cc));
    }
#pragma unroll
    for (int it = 0; it < 4; ++it) {
      int c = it * 256 + tid;
      int r = c >> 3, cc = (c & 7) * 8;
      int n = col0 + r; n = (n < N) ? n : (N - 1);
      rb[it] = *(const uint4*)(Bt + (long long)n * ldb + (k0 + cc));
    }
    __syncthreads();
#pragma unroll
    for (int it = 0; it < 4; ++it) {
      int c = it * 256 + tid;
      *(uint4*)&lA[c * 8] = ra[it];
      *(uint4*)&lB[c * 8] = rb[it];
    }
    __syncthreads();
#pragma unroll
    for (int ks = 0; ks < 2; ++ks) {
      int kb = ks * 32;
      bf16x8 af[4], bfr[4];
#pragma unroll
      for (int mi = 0; mi < 4; ++mi)
        af[mi] = *(const bf16x8*)&lA[(wm + mi * 16 + l16) * 64 + kb + quad * 8];
#pragma unroll
      for (int ni = 0; ni < 4; ++ni)
        bfr[ni] = *(const bf16x8*)&lB[(wn + ni * 16 + l16) * 64 + kb + quad * 8];
#pragma unroll
      for (int mi = 0; mi < 4; ++mi)
#pragma unroll
        for (int ni = 0; ni < 4; ++ni)
          acc[mi][ni] = __builtin_amdgcn_mfma_f32_16x16x32_bf16(
              af[mi], bfr[ni], acc[mi][ni], 0, 0, 0);
    }
  }

#pragma unroll
  for (int mi = 0; mi < 4; ++mi) {
#pragma unroll
    for (int ni = 0; ni < 4; ++ni) {
      int n = col0 + wn + ni * 16 + l16;
      if (n >= N) continue;
#pragma unroll
      for (int r = 0; r < 4; ++r) {
        int m = row0 + wm + mi * 16 + quad * 4 + r;
        float v = acc[mi][ni][r] * alpha;
        long long ci = coff + (long long)m * ldc + n;
        if (bias)  v += b2f(bias[n]);
        if (resid) v += resid[ci];
        if (outf)  outf[ci] = v;
        if (outb)  outb[ci] = f2b(v);
      }
    }
  }
}

// ---------------------------------------------------------------------------
// Split-K GEMM: outf[m][n] += A @ Bt^T over K-chunk z. fp32 atomic accumulate.
// ---------------------------------------------------------------------------
__global__ __launch_bounds__(256, 2) void gemm_splitk(
    const bf16* __restrict__ A, int lda,
    const bf16* __restrict__ Bt, int ldb,
    float* __restrict__ outf, int ldc, int KC)
{
  __shared__ __bf16 lA[128 * 64] __attribute__((aligned(16)));
  __shared__ __bf16 lB[128 * 64] __attribute__((aligned(16)));

  int koff = blockIdx.z * KC;
  int tid = threadIdx.x;
  int lane = tid & 63;
  int wave = tid >> 6;
  int quad = lane >> 4, l16 = lane & 15;
  int wm = (wave >> 1) * 64, wn = (wave & 1) * 64;
  int row0 = blockIdx.y * 128, col0 = blockIdx.x * 128;

  f32x4 acc[4][4];
#pragma unroll
  for (int a = 0; a < 4; ++a)
#pragma unroll
    for (int b = 0; b < 4; ++b) acc[a][b] = (f32x4){0.f, 0.f, 0.f, 0.f};

  for (int k0 = 0; k0 < KC; k0 += 64) {
    uint4 ra[4], rb[4];
#pragma unroll
    for (int it = 0; it < 4; ++it) {
      int c = it * 256 + tid;
      int r = c >> 3, cc = (c & 7) * 8;
      ra[it] = *(const uint4*)(A + (long long)(row0 + r) * lda + (koff + k0 + cc));
      rb[it] = *(const uint4*)(Bt + (long long)(col0 + r) * ldb + (koff + k0 + cc));
    }
    __syncthreads();
#pragma unroll
    for (int it = 0; it < 4; ++it) {
      int c = it * 256 + tid;
      *(uint4*)&lA[c * 8] = ra[it];
      *(uint4*)&lB[c * 8] = rb[it];
    }
    __syncthreads();
#pragma unroll
    for (int ks = 0; ks < 2; ++ks) {
      int kb = ks * 32;
      bf16x8 af[4], bfr[4];
#pragma unroll
      for (int mi = 0; mi < 4; ++mi)
        af[mi] = *(const bf16x8*)&lA[(wm + mi * 16 + l16) * 64 + kb + quad * 8];
#pragma unroll
      for (int ni = 0; ni < 4; ++ni)
        bfr[ni] = *(const bf16x8*)&lB[(wn + ni * 16 + l16) * 64 + kb + quad * 8];
#pragma unroll
      for (int mi = 0; mi < 4; ++mi)
#pragma unroll
        for (int ni = 0; ni < 4; ++ni)
          acc[mi][ni] = __builtin_amdgcn_mfma_f32_16x16x32_bf16(
              af[mi], bfr[ni], acc[mi][ni], 0, 0, 0);
    }
  }

#pragma unroll
  for (int mi = 0; mi < 4; ++mi)
#pragma unroll
    for (int ni = 0; ni < 4; ++ni) {
      int n = col0 + wn + ni * 16 + l16;
#pragma unroll
      for (int r = 0; r < 4; ++r) {
        int m = row0 + wm + mi * 16 + quad * 4 + r;
        atomicAdd(&outf[(long long)m * ldc + n], acc[mi][ni][r]);
      }
    }
}

// ---------------------------------------------------------------------------
// Fused flash attention. One WG per (b, h, q-half), 4 waves, 32 q-rows/wave.
// q [2048][1024]; k [8704][1024] (bias+rotary applied);
// vt [n=h*64+d][j=b*1088+jj] with ld 8704 (direct from V^T GEMM).
// All inner tile loops compile-time (TK template) so accS stays in registers.
// ---------------------------------------------------------------------------
template<int TK>
__device__ __forceinline__ void fa_tile(
    const bf16* __restrict__ kb, const bf16* __restrict__ vtb, int j0,
    const bf16x8 (&qa)[2][2], __bf16* lK, __bf16* lV, bf16* lPw,
    int tid, int quad, int l16,
    f32x4 (&accO)[2][4], f32x4 (&mrow)[2], f32x4 (&lrow)[2])
{
  constexpr int NT = TK / 16;
  constexpr int NCH = TK / 32;
  __syncthreads();
#pragma unroll
  for (int i = 0; i < TK / 32; ++i) {          // K-tile [TK][64]
    int t = i * 256 + tid;
    int r = t >> 3, c = (t & 7) * 8;
    *(uint4*)&lK[r * 72 + c] = *(const uint4*)&kb[(long long)(j0 + r) * 1024 + c];
  }
#pragma unroll
  for (int i = 0; i < TK / 32; ++i) {          // V^T-tile [64][TK]
    int t = i * 256 + tid;
    int d = t / (TK / 8), c = (t % (TK / 8)) * 8;
    *(uint4*)&lV[d * 136 + c] = *(const uint4*)&vtb[(long long)d * 8704 + j0 + c];
  }
  __syncthreads();

  f32x4 accS[2][NT];
#pragma unroll
  for (int mi = 0; mi < 2; ++mi)
#pragma unroll
    for (int ni = 0; ni < NT; ++ni) accS[mi][ni] = (f32x4){0.f, 0.f, 0.f, 0.f};

#pragma unroll
  for (int ni = 0; ni < NT; ++ni)
#pragma unroll
    for (int ks = 0; ks < 2; ++ks) {
      bf16x8 bfr = *(const bf16x8*)&lK[(ni * 16 + l16) * 72 + ks * 32 + quad * 8];
      accS[0][ni] = __builtin_amdgcn_mfma_f32_16x16x32_bf16(qa[0][ks], bfr, accS[0][ni], 0, 0, 0);
      accS[1][ni] = __builtin_amdgcn_mfma_f32_16x16x32_bf16(qa[1][ks], bfr, accS[1][ni], 0, 0, 0);
    }

#pragma unroll
  for (int mi = 0; mi < 2; ++mi) {
    f32x4 vmax = (f32x4){-INFINITY, -INFINITY, -INFINITY, -INFINITY};
#pragma unroll
    for (int ni = 0; ni < NT; ++ni) {
      accS[mi][ni] *= 0.125f;
      vmax = max4(vmax, accS[mi][ni]);
    }
#pragma unroll
    for (int m = 1; m <= 8; m <<= 1) vmax = max4(vmax, shfl_xor4(vmax, m));
    f32x4 mnew = max4(mrow[mi], vmax);
    f32x4 alpha = exp4(mrow[mi] - mnew);
    f32x4 rs = (f32x4){0.f, 0.f, 0.f, 0.f};
#pragma unroll
    for (int ni = 0; ni < NT; ++ni) {
      accS[mi][ni] = exp4(accS[mi][ni] - mnew);
      rs += accS[mi][ni];
    }
#pragma unroll
    for (int m = 1; m <= 8; m <<= 1) rs += shfl_xor4(rs, m);
    lrow[mi] = lrow[mi] * alpha + rs;
    mrow[mi] = mnew;
#pragma unroll
    for (int nd = 0; nd < 4; ++nd) accO[mi][nd] *= alpha;
  }

#pragma unroll
  for (int c = 0; c < NCH; ++c) {
#pragma unroll
    for (int mi = 0; mi < 2; ++mi)
#pragma unroll
      for (int u = 0; u < 2; ++u) {
#pragma unroll
        for (int r = 0; r < 4; ++r)
          lPw[(mi * 16 + quad * 4 + r) * 40 + u * 16 + l16] = f2b(accS[mi][c * 2 + u][r]);
      }
#pragma unroll
    for (int nd = 0; nd < 4; ++nd) {
      bf16x8 vb = *(const bf16x8*)&lV[(nd * 16 + l16) * 136 + c * 32 + quad * 8];
      bf16x8 pa0 = *(const bf16x8*)&lPw[(l16) * 40 + quad * 8];
      bf16x8 pa1 = *(const bf16x8*)&lPw[(16 + l16) * 40 + quad * 8];
      accO[0][nd] = __builtin_amdgcn_mfma_f32_16x16x32_bf16(pa0, vb, accO[0][nd], 0, 0, 0);
      accO[1][nd] = __builtin_amdgcn_mfma_f32_16x16x32_bf16(pa1, vb, accO[1][nd], 0, 0, 0);
    }
  }
}

__global__ __launch_bounds__(256, 1) void flash_attn(
    const bf16* __restrict__ q, const bf16* __restrict__ k,
    const bf16* __restrict__ vt, bf16* __restrict__ att)
{
  __shared__ __bf16 lK[128 * 72] __attribute__((aligned(16)));
  __shared__ __bf16 lV[64 * 136] __attribute__((aligned(16)));
  __shared__ __bf16 lP[4][32 * 40] __attribute__((aligned(16)));

  int idx = blockIdx.x;                 // 0..255
  int b = idx >> 5, h = (idx >> 1) & 15, half = idx & 1;
  int tid = threadIdx.x, wave = tid >> 6, lane = tid & 63;
  int quad = lane >> 4, l16 = lane & 15;
  int qrow0 = b * 256 + half * 128 + wave * 32;

  const bf16* kb  = k  + (long long)b * 1088 * 1024 + h * 64;
  const bf16* vtb = vt + (long long)(h * 64) * 8704 + b * 1088;
  bf16* lPw = (bf16*)&lP[wave][0];

  bf16x8 qa[2][2];
#pragma unroll
  for (int mi = 0; mi < 2; ++mi)
#pragma unroll
    for (int ks = 0; ks < 2; ++ks)
      qa[mi][ks] = *(const bf16x8*)&q[(long long)(qrow0 + mi * 16 + l16) * 1024 +
                                      h * 64 + ks * 32 + quad * 8];

  f32x4 accO[2][4];
  f32x4 mrow[2], lrow[2];
#pragma unroll
  for (int mi = 0; mi < 2; ++mi) {
    mrow[mi] = (f32x4){-INFINITY, -INFINITY, -INFINITY, -INFINITY};
    lrow[mi] = (f32x4){0.f, 0.f, 0.f, 0.f};
#pragma unroll
    for (int nd = 0; nd < 4; ++nd) accO[mi][nd] = (f32x4){0.f, 0.f, 0.f, 0.f};
  }

  for (int jt = 0; jt < 8; ++jt)
    fa_tile<128>(kb, vtb, jt * 128, qa, lK, lV, lPw, tid, quad, l16, accO, mrow, lrow);
  fa_tile<64>(kb, vtb, 1024, qa, lK, lV, lPw, tid, quad, l16, accO, mrow, lrow);

#pragma unroll
  for (int mi = 0; mi < 2; ++mi) {
    f32x4 inv;
    inv[0] = 1.f / lrow[mi][0]; inv[1] = 1.f / lrow[mi][1];
    inv[2] = 1.f / lrow[mi][2]; inv[3] = 1.f / lrow[mi][3];
#pragma unroll
    for (int nd = 0; nd < 4; ++nd) {
      f32x4 o = accO[mi][nd] * inv;
#pragma unroll
      for (int r = 0; r < 4; ++r)
        att[(long long)(qrow0 + mi * 16 + quad * 4 + r) * 1024 +
            h * 64 + nd * 16 + l16] = f2b(o[r]);
    }
  }
}

// ---------------------------------------------------------------------------
// Elementwise / helper kernels
// ---------------------------------------------------------------------------
__global__ void init_x_kernel(const void* __restrict__ x, const int* __restrict__ flag,
                              float* __restrict__ xf, bf16* __restrict__ xbf) {
  int i = blockIdx.x * 256 + threadIdx.x;
  float v = (*flag) ? b2f(((const bf16*)x)[i]) : ((const float*)x)[i];
  xf[i] = v;
  xbf[i] = f2b(v);
}

__global__ void transpose_w(const void* __restrict__ in, bf16* __restrict__ out,
                            int R, int C, const int* __restrict__ flag) {
  __shared__ bf16 tile[32][33];
  long long zoff = (long long)blockIdx.z * R * C;
  const bf16* inb = (const bf16*)in + zoff;
  const float* inf = (const float*)in + zoff;
  out += zoff;
  int tx = threadIdx.x, ty = threadIdx.y;
  int c0 = blockIdx.x * 32, r0 = blockIdx.y * 32;
  int isb = *flag;
#pragma unroll
  for (int i = 0; i < 4; ++i) {
    long long off = (long long)(r0 + ty + i * 8) * C + (c0 + tx);
    tile[ty + i * 8][tx] = isb ? inb[off] : f2b(inf[off]);
  }
  __syncthreads();
#pragma unroll
  for (int i = 0; i < 4; ++i)
    out[(long long)(c0 + ty + i * 8) * R + (r0 + tx)] = tile[tx][ty + i * 8];
}

__global__ void rotary_q_kernel(bf16* __restrict__ q, const bf16* __restrict__ srcf) {
  int idx = blockIdx.x * 256 + threadIdx.x;
  int row = idx >> 9;
  int p = idx & 511;
  int h = p >> 5, i = p & 31;
  int d0 = h * 64 + 2 * i;
  int ntok = row & 255;
  float f = b2f(srcf[ntok * 64 + 2 * i]);
  float c = cosf(f), s = sinf(f);
  long long base = (long long)row * 1024 + d0;
  float q0 = b2f(q[base]), q1 = b2f(q[base + 1]);
  q[base]     = f2b(q0 * c - q1 * s);
  q[base + 1] = f2b(q1 * c + q0 * s);
}

__global__ void k_bias_rot_kernel(bf16* __restrict__ k, const bf16* __restrict__ tgtf,
                                  const bf16* __restrict__ rpe,
                                  const int* __restrict__ ridx, int layer) {
  int idx = blockIdx.x * 256 + threadIdx.x;
  int b = idx >> 19;
  int rem = idx & ((1 << 19) - 1);
  int j = rem >> 9;
  int p = rem & 511;
  int h = p >> 5, i = p & 31;
  int d0 = h * 64 + 2 * i;
  float bias = b2f(rpe[(layer * 405 + ridx[j >> 8]) * 16 + h]);
  float f = b2f(tgtf[j * 64 + 2 * i]);
  float c = cosf(f), s = sinf(f);
  long long base = (long long)(b * 1088 + j) * 1024 + d0;
  float k0 = b2f(k[base]) + bias, k1 = b2f(k[base + 1]) + bias;
  k[base]     = f2b(k0 * c - k1 * s);
  k[base + 1] = f2b(k1 * c + k0 * s);
}

__global__ void geglu_kernel(const bf16* __restrict__ hgl, bf16* __restrict__ y) {
  int idx = blockIdx.x * 256 + threadIdx.x;
  int m = idx >> 12, n = idx & 4095;
  float a = b2f(hgl[(long long)m * 8192 + n]);
  float g = b2f(hgl[(long long)m * 8192 + 4096 + n]);
  float ge = 0.5f * g * (1.0f + erff(g * 0.70710678118654752f));
  y[idx] = f2b(a * ge);
}

// xf[i] += bias[i % 1024]   (pre-FF2 bias so split-K can atomically accumulate)
__global__ void bias_add_f(float* __restrict__ xf, const bf16* __restrict__ bias) {
  int i = blockIdx.x * 256 + threadIdx.x;
  xf[i] += b2f(bias[i & 1023]);
}

__global__ void xf_to_xbf(const float* __restrict__ xf, bf16* __restrict__ xbf) {
  int i = blockIdx.x * 256 + threadIdx.x;
  xbf[i] = f2b(xf[i]);
}

// ---------------------------------------------------------------------------
static void launch_gemm(hipStream_t st,
    const bf16* A, long long sAb, long long sAh, int lda,
    const bf16* Bt, long long sBb, long long sBh, int ldb,
    float alpha, const float* resid, const bf16* bias,
    float* outf, bf16* outb, long long sCb, long long sCh, int ldc,
    int M, int N, int K, int batches)
{
  dim3 grid((N + 127) / 128, M / 128, batches);
  gemm_bt<<<grid, dim3(256), 0, st>>>(A, sAb, sAh, lda, Bt, sBb, sBh, ldb, alpha,
                                      resid, bias, outf, outb, sCb, sCh, ldc, M, N, K);
}

extern "C" void kernel_launch(void* const* d_in, const int* in_sizes, int n_in,
                              void* d_out, int out_size, void* d_ws, size_t ws_size,
                              hipStream_t stream) {
  (void)in_sizes; (void)n_in; (void)out_size; (void)ws_size;
  const void* x    = d_in[0];
  const void* cond = d_in[1];
  const void* Wq   = d_in[2];
  const void* Wk   = d_in[3];
  const void* Wv   = d_in[4];
  const void* Wo   = d_in[5];
  const void* bo   = d_in[6];
  const void* rpe  = d_in[7];
  const void* W1   = d_in[8];
  const void* b1   = d_in[9];
  const void* W2   = d_in[10];
  const void* b2   = d_in[11];
  const void* srcf = d_in[12];
  const void* tgtf = d_in[13];
  const int*  ridx = (const int*)d_in[14];

  char* w = (char*)d_ws;
  int* flag = (int*)w;   w += 256;
  bf16* WqT = (bf16*)w;  w += (size_t)2 * 1024 * 1024 * 2;
  bf16* WkT = (bf16*)w;  w += (size_t)2 * 1024 * 1024 * 2;
  bf16* WvT = (bf16*)w;  w += (size_t)2 * 1024 * 1024 * 2;
  bf16* WoT = (bf16*)w;  w += (size_t)2 * 1024 * 1024 * 2;
  bf16* W1T = (bf16*)w;  w += (size_t)2 * 8192 * 1024 * 2;
  bf16* W2T = (bf16*)w;  w += (size_t)2 * 4096 * 1024 * 2;
  bf16* condb = (bf16*)w; w += (size_t)8704 * 1024 * 2;
  bf16* bo_b = (bf16*)w;  w += 2048 * 2;
  bf16* rpe_b = (bf16*)w; w += 12960 * 2;
  bf16* b1_b = (bf16*)w;  w += 16384 * 2;
  bf16* b2_b = (bf16*)w;  w += 2048 * 2;
  bf16* srcf_b = (bf16*)w; w += 16384 * 2;
  bf16* tgtf_b = (bf16*)w; w += 65536 * 2;
  float* xf = (float*)w; w += (size_t)2048 * 1024 * 4;
  bf16* xbf = (bf16*)w;  w += (size_t)2048 * 1024 * 2;
  bf16* qbuf = (bf16*)w; w += (size_t)2048 * 1024 * 2;
  bf16* kbuf = (bf16*)w; w += (size_t)8704 * 1024 * 2;
  bf16* vTf = (bf16*)w;  w += (size_t)1024 * 8704 * 2;   // V^T direct from GEMM
  bf16* att = (bf16*)w;  w += (size_t)2048 * 1024 * 2;
  bf16* hgl = (bf16*)w;  w += (size_t)2048 * 8192 * 2;
  bf16* ybuf = (bf16*)w; w += (size_t)2048 * 4096 * 2;

  detect_dtype<<<1, 1, 0, stream>>>((const unsigned int*)x, flag);

  convert_in<<<34816, 256, 0, stream>>>(cond, condb, 8704 * 1024, flag);
  convert_in<<<8, 256, 0, stream>>>(bo, bo_b, 2048, flag);
  convert_in<<<51, 256, 0, stream>>>(rpe, rpe_b, 12960, flag);
  convert_in<<<64, 256, 0, stream>>>(b1, b1_b, 16384, flag);
  convert_in<<<8, 256, 0, stream>>>(b2, b2_b, 2048, flag);
  convert_in<<<64, 256, 0, stream>>>(srcf, srcf_b, 16384, flag);
  convert_in<<<256, 256, 0, stream>>>(tgtf, tgtf_b, 65536, flag);

  dim3 tb(32, 8);
  transpose_w<<<dim3(32, 32, 2),  tb, 0, stream>>>(Wq, WqT, 1024, 1024, flag);
  transpose_w<<<dim3(32, 32, 2),  tb, 0, stream>>>(Wk, WkT, 1024, 1024, flag);
  transpose_w<<<dim3(32, 32, 2),  tb, 0, stream>>>(Wv, WvT, 1024, 1024, flag);
  transpose_w<<<dim3(32, 32, 2),  tb, 0, stream>>>(Wo, WoT, 1024, 1024, flag);
  transpose_w<<<dim3(256, 32, 2), tb, 0, stream>>>(W1, W1T, 1024, 8192, flag);
  transpose_w<<<dim3(32, 128, 2), tb, 0, stream>>>(W2, W2T, 4096, 1024, flag);
  init_x_kernel<<<8192, 256, 0, stream>>>(x, flag, xf, xbf);

  for (int l = 0; l < 2; ++l) {
    const bf16* WqTl = WqT + (size_t)l * 1024 * 1024;
    const bf16* WkTl = WkT + (size_t)l * 1024 * 1024;
    const bf16* WvTl = WvT + (size_t)l * 1024 * 1024;
    const bf16* WoTl = WoT + (size_t)l * 1024 * 1024;
    const bf16* W1Tl = W1T + (size_t)l * 8192 * 1024;
    const bf16* W2Tl = W2T + (size_t)l * 4096 * 1024;

    // q = x @ Wq ; rotary
    launch_gemm(stream, xbf, 0, 0, 1024, WqTl, 0, 0, 1024, 1.f,
                nullptr, nullptr, nullptr, qbuf, 0, 0, 1024, 2048, 1024, 1024, 1);
    rotary_q_kernel<<<4096, 256, 0, stream>>>(qbuf, srcf_b);
    // V^T directly: vTf[n][j] = sum_k WvT[n][k] cond[j][k]  (M=1024, N=8704)
    launch_gemm(stream, WvTl, 0, 0, 1024, condb, 0, 0, 1024, 1.f,
                nullptr, nullptr, nullptr, vTf, 0, 0, 8704, 1024, 8704, 1024, 1);
    // k = cond @ Wk ; bias + rotary on memory part
    launch_gemm(stream, condb, 0, 0, 1024, WkTl, 0, 0, 1024, 1.f,
                nullptr, nullptr, nullptr, kbuf, 0, 0, 1024, 8704, 1024, 1024, 1);
    k_bias_rot_kernel<<<16384, 256, 0, stream>>>(kbuf, tgtf_b, rpe_b, ridx, l);
    // fused attention
    flash_attn<<<256, 256, 0, stream>>>(qbuf, kbuf, vTf, att);
    // x = x + O @ Wo + bo
    launch_gemm(stream, att, 0, 0, 1024, WoTl, 0, 0, 1024, 1.f,
                xf, bo_b + (size_t)l * 1024, xf, xbf, 0, 0, 1024, 2048, 1024, 1024, 1);
    // FF1: hgl = x @ W1 + b1
    launch_gemm(stream, xbf, 0, 0, 1024, W1Tl, 0, 0, 1024, 1.f,
                nullptr, b1_b + (size_t)l * 8192, nullptr, hgl, 0, 0, 8192, 2048, 8192, 1024, 1);
    geglu_kernel<<<32768, 256, 0, stream>>>(hgl, ybuf);
    // FF2 (split-K): xf += b2 ; xf += y @ W2 (4 K-chunks, atomic) ; xbf = bf16(xf)
    bias_add_f<<<8192, 256, 0, stream>>>(xf, b2_b + (size_t)l * 1024);
    gemm_splitk<<<dim3(8, 16, 4), dim3(256), 0, stream>>>(ybuf, 4096, W2Tl, 4096,
                                                          xf, 1024, 1024);
    xf_to_xbf<<<8192, 256, 0, stream>>>(xf, xbf);
  }

  emit_kernel<<<8192, 256, 0, stream>>>(xf, flag, d_out);
}

// Round 6
// 1845.763 us; speedup vs baseline: 1.2620x; 1.0037x over previous
//
#include <hip/hip_runtime.h>
#include <hip/hip_bf16.h>
#include <math.h>

typedef __hip_bfloat16 bf16;
typedef __bf16 bf16x8 __attribute__((ext_vector_type(8)));
typedef float f32x4 __attribute__((ext_vector_type(4)));

__device__ __forceinline__ float b2f(bf16 v) { return __bfloat162float(v); }
__device__ __forceinline__ bf16 f2b(float v) { return __float2bfloat16(v); }

__device__ __forceinline__ f32x4 shfl_xor4(f32x4 v, int m) {
  f32x4 o;
  o[0] = __shfl_xor(v[0], m);
  o[1] = __shfl_xor(v[1], m);
  o[2] = __shfl_xor(v[2], m);
  o[3] = __shfl_xor(v[3], m);
  return o;
}
__device__ __forceinline__ f32x4 max4(f32x4 a, f32x4 b) {
  f32x4 o;
  o[0] = fmaxf(a[0], b[0]); o[1] = fmaxf(a[1], b[1]);
  o[2] = fmaxf(a[2], b[2]); o[3] = fmaxf(a[3], b[3]);
  return o;
}
__device__ __forceinline__ f32x4 exp4(f32x4 a) {
  f32x4 o;
  o[0] = __expf(a[0]); o[1] = __expf(a[1]);
  o[2] = __expf(a[2]); o[3] = __expf(a[3]);
  return o;
}

// ---------------------------------------------------------------------------
// dtype detection (inputs bf16 vs fp32), device-side, deterministic per call
// ---------------------------------------------------------------------------
__global__ void detect_dtype(const unsigned int* __restrict__ x, int* __restrict__ flag) {
  int cnt = 0;
  for (int i = 0; i < 128; ++i) {
    unsigned int lo = x[i] & 0xFFFFu;
    unsigned int e = (lo >> 7) & 0xFFu;
    if (e >= 100u && e <= 140u) ++cnt;
  }
  *flag = (cnt >= 96) ? 1 : 0;
}

__global__ void convert_in(const void* __restrict__ src, bf16* __restrict__ dst,
                           int n, const int* __restrict__ flag) {
  int i = blockIdx.x * 256 + threadIdx.x;
  if (i >= n) return;
  dst[i] = (*flag) ? ((const bf16*)src)[i] : f2b(((const float*)src)[i]);
}

__global__ void emit_kernel(const float* __restrict__ xf, const int* __restrict__ flag,
                            void* __restrict__ out) {
  int i = blockIdx.x * 256 + threadIdx.x;
  if (*flag) ((bf16*)out)[i] = f2b(xf[i]);
  else       ((float*)out)[i] = xf[i];
}

// ---------------------------------------------------------------------------
// Generic GEMM: C = alpha * A @ Bt^T (+bias +resid), bf16 in, fp32 acc.
// M, N multiples of 128; K multiple of 64 (no ragged handling).
// Epilogue: C tile staged through LDS (fp32) -> full-line vectorized stores.
// TAG only differentiates mangled names for per-dispatch rocprof attribution.
// ---------------------------------------------------------------------------
template<int TAG>
__global__ __launch_bounds__(256, 2) void gemm_bt(
    const bf16* __restrict__ A, int lda,
    const bf16* __restrict__ Bt, int ldb,
    float alpha,
    const float* __restrict__ resid,
    const bf16* __restrict__ bias,
    float* __restrict__ outf,
    bf16* __restrict__ outb,
    int ldc, int K)
{
  __shared__ char smem[32768] __attribute__((aligned(16)));
  __bf16* lA = (__bf16*)smem;
  __bf16* lB = (__bf16*)(smem + 16384);
  float*  lC = (float*)smem;           // epilogue alias (32 KB = 64x128 f32)

  int tid = threadIdx.x;
  int lane = tid & 63;
  int wave = tid >> 6;
  int quad = lane >> 4, l16 = lane & 15;
  int wm = (wave >> 1) * 64, wn = (wave & 1) * 64;
  int row0 = blockIdx.y * 128, col0 = blockIdx.x * 128;

  f32x4 acc[4][4];
#pragma unroll
  for (int a = 0; a < 4; ++a)
#pragma unroll
    for (int b = 0; b < 4; ++b) acc[a][b] = (f32x4){0.f, 0.f, 0.f, 0.f};

  for (int k0 = 0; k0 < K; k0 += 64) {
    uint4 ra[4], rb[4];
#pragma unroll
    for (int it = 0; it < 4; ++it) {
      int c = it * 256 + tid;
      int r = c >> 3, cc = (c & 7) * 8;
      ra[it] = *(const uint4*)(A + (long long)(row0 + r) * lda + (k0 + cc));
      rb[it] = *(const uint4*)(Bt + (long long)(col0 + r) * ldb + (k0 + cc));
    }
    __syncthreads();
#pragma unroll
    for (int it = 0; it < 4; ++it) {
      int c = it * 256 + tid;
      *(uint4*)&lA[c * 8] = ra[it];
      *(uint4*)&lB[c * 8] = rb[it];
    }
    __syncthreads();
#pragma unroll
    for (int ks = 0; ks < 2; ++ks) {
      int kb = ks * 32;
      bf16x8 af[4], bfr[4];
#pragma unroll
      for (int mi = 0; mi < 4; ++mi)
        af[mi] = *(const bf16x8*)&lA[(wm + mi * 16 + l16) * 64 + kb + quad * 8];
#pragma unroll
      for (int ni = 0; ni < 4; ++ni)
        bfr[ni] = *(const bf16x8*)&lB[(wn + ni * 16 + l16) * 64 + kb + quad * 8];
#pragma unroll
      for (int mi = 0; mi < 4; ++mi)
#pragma unroll
        for (int ni = 0; ni < 4; ++ni)
          acc[mi][ni] = __builtin_amdgcn_mfma_f32_16x16x32_bf16(
              af[mi], bfr[ni], acc[mi][ni], 0, 0, 0);
    }
  }

  // --- LDS epilogue: two halves of 64 rows; full-line vectorized stores ---
#pragma unroll
  for (int half = 0; half < 2; ++half) {
    __syncthreads();
    if ((wave >> 1) == half) {
#pragma unroll
      for (int mi = 0; mi < 4; ++mi)
#pragma unroll
        for (int ni = 0; ni < 4; ++ni)
#pragma unroll
          for (int r = 0; r < 4; ++r)
            lC[(mi * 16 + quad * 4 + r) * 128 + wn + ni * 16 + l16] =
                acc[mi][ni][r] * alpha;
    }
    __syncthreads();
#pragma unroll
    for (int i = 0; i < 8; ++i) {
      int f = i * 256 + tid;             // 0..2047
      int row = f >> 5, cc = (f & 31) * 4;
      int m = row0 + half * 64 + row, n = col0 + cc;
      f32x4 v = *(const f32x4*)&lC[row * 128 + cc];
      long long ci = (long long)m * ldc + n;
      if (bias) {
        v[0] += b2f(bias[n]);     v[1] += b2f(bias[n + 1]);
        v[2] += b2f(bias[n + 2]); v[3] += b2f(bias[n + 3]);
      }
      if (resid) v += *(const f32x4*)&resid[ci];
      if (outf) *(f32x4*)&outf[ci] = v;
      if (outb) {
        bf16 c0 = f2b(v[0]), c1 = f2b(v[1]), c2 = f2b(v[2]), c3 = f2b(v[3]);
        ushort4 o = { *(unsigned short*)&c0, *(unsigned short*)&c1,
                      *(unsigned short*)&c2, *(unsigned short*)&c3 };
        *(ushort4*)&outb[ci] = o;
      }
    }
  }
}

// ---------------------------------------------------------------------------
// Split-K GEMM: pbuf[z][m][n] = A(K-chunk z) @ Bt^T. Plain dword stores.
// ---------------------------------------------------------------------------
__global__ __launch_bounds__(256, 2) void gemm_splitk(
    const bf16* __restrict__ A, int lda,
    const bf16* __restrict__ Bt, int ldb,
    float* __restrict__ pbuf, int ldc, int M, int KC)
{
  __shared__ __bf16 lA[128 * 64] __attribute__((aligned(16)));
  __shared__ __bf16 lB[128 * 64] __attribute__((aligned(16)));

  int koff = blockIdx.z * KC;
  float* outz = pbuf + (long long)blockIdx.z * M * ldc;
  int tid = threadIdx.x;
  int lane = tid & 63;
  int wave = tid >> 6;
  int quad = lane >> 4, l16 = lane & 15;
  int wm = (wave >> 1) * 64, wn = (wave & 1) * 64;
  int row0 = blockIdx.y * 128, col0 = blockIdx.x * 128;

  f32x4 acc[4][4];
#pragma unroll
  for (int a = 0; a < 4; ++a)
#pragma unroll
    for (int b = 0; b < 4; ++b) acc[a][b] = (f32x4){0.f, 0.f, 0.f, 0.f};

  for (int k0 = 0; k0 < KC; k0 += 64) {
    uint4 ra[4], rb[4];
#pragma unroll
    for (int it = 0; it < 4; ++it) {
      int c = it * 256 + tid;
      int r = c >> 3, cc = (c & 7) * 8;
      ra[it] = *(const uint4*)(A + (long long)(row0 + r) * lda + (koff + k0 + cc));
      rb[it] = *(const uint4*)(Bt + (long long)(col0 + r) * ldb + (koff + k0 + cc));
    }
    __syncthreads();
#pragma unroll
    for (int it = 0; it < 4; ++it) {
      int c = it * 256 + tid;
      *(uint4*)&lA[c * 8] = ra[it];
      *(uint4*)&lB[c * 8] = rb[it];
    }
    __syncthreads();
#pragma unroll
    for (int ks = 0; ks < 2; ++ks) {
      int kb = ks * 32;
      bf16x8 af[4], bfr[4];
#pragma unroll
      for (int mi = 0; mi < 4; ++mi)
        af[mi] = *(const bf16x8*)&lA[(wm + mi * 16 + l16) * 64 + kb + quad * 8];
#pragma unroll
      for (int ni = 0; ni < 4; ++ni)
        bfr[ni] = *(const bf16x8*)&lB[(wn + ni * 16 + l16) * 64 + kb + quad * 8];
#pragma unroll
      for (int mi = 0; mi < 4; ++mi)
#pragma unroll
        for (int ni = 0; ni < 4; ++ni)
          acc[mi][ni] = __builtin_amdgcn_mfma_f32_16x16x32_bf16(
              af[mi], bfr[ni], acc[mi][ni], 0, 0, 0);
    }
  }

#pragma unroll
  for (int mi = 0; mi < 4; ++mi)
#pragma unroll
    for (int ni = 0; ni < 4; ++ni) {
      int n = col0 + wn + ni * 16 + l16;
#pragma unroll
      for (int r = 0; r < 4; ++r) {
        int m = row0 + wm + mi * 16 + quad * 4 + r;
        outz[(long long)m * ldc + n] = acc[mi][ni][r];
      }
    }
}

// reduce 4 split-K partials + b2 + residual -> xf (fp32) and xbf (bf16)
__global__ void reduce_ff2(const float* __restrict__ pbuf, const bf16* __restrict__ bias,
                           float* __restrict__ xf, bf16* __restrict__ xbf) {
  int i = blockIdx.x * 256 + threadIdx.x;   // [0, 2048*1024)
  const int NT = 2048 * 1024;
  float v = xf[i] + b2f(bias[i & 1023]) +
            pbuf[i] + pbuf[i + NT] + pbuf[i + 2 * NT] + pbuf[i + 3 * NT];
  xf[i] = v;
  xbf[i] = f2b(v);
}

// ---------------------------------------------------------------------------
// Fused flash attention (unchanged from round 5)
// ---------------------------------------------------------------------------
template<int TK>
__device__ __forceinline__ void fa_tile(
    const bf16* __restrict__ kb, const bf16* __restrict__ vtb, int j0,
    const bf16x8 (&qa)[2][2], __bf16* lK, __bf16* lV, bf16* lPw,
    int tid, int quad, int l16,
    f32x4 (&accO)[2][4], f32x4 (&mrow)[2], f32x4 (&lrow)[2])
{
  constexpr int NT = TK / 16;
  constexpr int NCH = TK / 32;
  __syncthreads();
#pragma unroll
  for (int i = 0; i < TK / 32; ++i) {
    int t = i * 256 + tid;
    int r = t >> 3, c = (t & 7) * 8;
    *(uint4*)&lK[r * 72 + c] = *(const uint4*)&kb[(long long)(j0 + r) * 1024 + c];
  }
#pragma unroll
  for (int i = 0; i < TK / 32; ++i) {
    int t = i * 256 + tid;
    int d = t / (TK / 8), c = (t % (TK / 8)) * 8;
    *(uint4*)&lV[d * 136 + c] = *(const uint4*)&vtb[(long long)d * 8704 + j0 + c];
  }
  __syncthreads();

  f32x4 accS[2][NT];
#pragma unroll
  for (int mi = 0; mi < 2; ++mi)
#pragma unroll
    for (int ni = 0; ni < NT; ++ni) accS[mi][ni] = (f32x4){0.f, 0.f, 0.f, 0.f};

#pragma unroll
  for (int ni = 0; ni < NT; ++ni)
#pragma unroll
    for (int ks = 0; ks < 2; ++ks) {
      bf16x8 bfr = *(const bf16x8*)&lK[(ni * 16 + l16) * 72 + ks * 32 + quad * 8];
      accS[0][ni] = __builtin_amdgcn_mfma_f32_16x16x32_bf16(qa[0][ks], bfr, accS[0][ni], 0, 0, 0);
      accS[1][ni] = __builtin_amdgcn_mfma_f32_16x16x32_bf16(qa[1][ks], bfr, accS[1][ni], 0, 0, 0);
    }

#pragma unroll
  for (int mi = 0; mi < 2; ++mi) {
    f32x4 vmax = (f32x4){-INFINITY, -INFINITY, -INFINITY, -INFINITY};
#pragma unroll
    for (int ni = 0; ni < NT; ++ni) {
      accS[mi][ni] *= 0.125f;
      vmax = max4(vmax, accS[mi][ni]);
    }
#pragma unroll
    for (int m = 1; m <= 8; m <<= 1) vmax = max4(vmax, shfl_xor4(vmax, m));
    f32x4 mnew = max4(mrow[mi], vmax);
    f32x4 alpha = exp4(mrow[mi] - mnew);
    f32x4 rs = (f32x4){0.f, 0.f, 0.f, 0.f};
#pragma unroll
    for (int ni = 0; ni < NT; ++ni) {
      accS[mi][ni] = exp4(accS[mi][ni] - mnew);
      rs += accS[mi][ni];
    }
#pragma unroll
    for (int m = 1; m <= 8; m <<= 1) rs += shfl_xor4(rs, m);
    lrow[mi] = lrow[mi] * alpha + rs;
    mrow[mi] = mnew;
#pragma unroll
    for (int nd = 0; nd < 4; ++nd) accO[mi][nd] *= alpha;
  }

#pragma unroll
  for (int c = 0; c < NCH; ++c) {
#pragma unroll
    for (int mi = 0; mi < 2; ++mi)
#pragma unroll
      for (int u = 0; u < 2; ++u) {
#pragma unroll
        for (int r = 0; r < 4; ++r)
          lPw[(mi * 16 + quad * 4 + r) * 40 + u * 16 + l16] = f2b(accS[mi][c * 2 + u][r]);
      }
#pragma unroll
    for (int nd = 0; nd < 4; ++nd) {
      bf16x8 vb = *(const bf16x8*)&lV[(nd * 16 + l16) * 136 + c * 32 + quad * 8];
      bf16x8 pa0 = *(const bf16x8*)&lPw[(l16) * 40 + quad * 8];
      bf16x8 pa1 = *(const bf16x8*)&lPw[(16 + l16) * 40 + quad * 8];
      accO[0][nd] = __builtin_amdgcn_mfma_f32_16x16x32_bf16(pa0, vb, accO[0][nd], 0, 0, 0);
      accO[1][nd] = __builtin_amdgcn_mfma_f32_16x16x32_bf16(pa1, vb, accO[1][nd], 0, 0, 0);
    }
  }
}

__global__ __launch_bounds__(256, 1) void flash_attn(
    const bf16* __restrict__ q, const bf16* __restrict__ k,
    const bf16* __restrict__ vt, bf16* __restrict__ att)
{
  __shared__ __bf16 lK[128 * 72] __attribute__((aligned(16)));
  __shared__ __bf16 lV[64 * 136] __attribute__((aligned(16)));
  __shared__ __bf16 lP[4][32 * 40] __attribute__((aligned(16)));

  int idx = blockIdx.x;
  int b = idx >> 5, h = (idx >> 1) & 15, half = idx & 1;
  int tid = threadIdx.x, wave = tid >> 6, lane = tid & 63;
  int quad = lane >> 4, l16 = lane & 15;
  int qrow0 = b * 256 + half * 128 + wave * 32;

  const bf16* kb  = k  + (long long)b * 1088 * 1024 + h * 64;
  const bf16* vtb = vt + (long long)(h * 64) * 8704 + b * 1088;
  bf16* lPw = (bf16*)&lP[wave][0];

  bf16x8 qa[2][2];
#pragma unroll
  for (int mi = 0; mi < 2; ++mi)
#pragma unroll
    for (int ks = 0; ks < 2; ++ks)
      qa[mi][ks] = *(const bf16x8*)&q[(long long)(qrow0 + mi * 16 + l16) * 1024 +
                                      h * 64 + ks * 32 + quad * 8];

  f32x4 accO[2][4];
  f32x4 mrow[2], lrow[2];
#pragma unroll
  for (int mi = 0; mi < 2; ++mi) {
    mrow[mi] = (f32x4){-INFINITY, -INFINITY, -INFINITY, -INFINITY};
    lrow[mi] = (f32x4){0.f, 0.f, 0.f, 0.f};
#pragma unroll
    for (int nd = 0; nd < 4; ++nd) accO[mi][nd] = (f32x4){0.f, 0.f, 0.f, 0.f};
  }

  for (int jt = 0; jt < 8; ++jt)
    fa_tile<128>(kb, vtb, jt * 128, qa, lK, lV, lPw, tid, quad, l16, accO, mrow, lrow);
  fa_tile<64>(kb, vtb, 1024, qa, lK, lV, lPw, tid, quad, l16, accO, mrow, lrow);

#pragma unroll
  for (int mi = 0; mi < 2; ++mi) {
    f32x4 inv;
    inv[0] = 1.f / lrow[mi][0]; inv[1] = 1.f / lrow[mi][1];
    inv[2] = 1.f / lrow[mi][2]; inv[3] = 1.f / lrow[mi][3];
#pragma unroll
    for (int nd = 0; nd < 4; ++nd) {
      f32x4 o = accO[mi][nd] * inv;
#pragma unroll
      for (int r = 0; r < 4; ++r)
        att[(long long)(qrow0 + mi * 16 + quad * 4 + r) * 1024 +
            h * 64 + nd * 16 + l16] = f2b(o[r]);
    }
  }
}

// ---------------------------------------------------------------------------
// Elementwise / helper kernels
// ---------------------------------------------------------------------------
__global__ void init_x_kernel(const void* __restrict__ x, const int* __restrict__ flag,
                              float* __restrict__ xf, bf16* __restrict__ xbf) {
  int i = blockIdx.x * 256 + threadIdx.x;
  float v = (*flag) ? b2f(((const bf16*)x)[i]) : ((const float*)x)[i];
  xf[i] = v;
  xbf[i] = f2b(v);
}

__global__ void transpose_w(const void* __restrict__ in, bf16* __restrict__ out,
                            int R, int C, const int* __restrict__ flag) {
  __shared__ bf16 tile[32][33];
  long long zoff = (long long)blockIdx.z * R * C;
  const bf16* inb = (const bf16*)in + zoff;
  const float* inf = (const float*)in + zoff;
  out += zoff;
  int tx = threadIdx.x, ty = threadIdx.y;
  int c0 = blockIdx.x * 32, r0 = blockIdx.y * 32;
  int isb = *flag;
#pragma unroll
  for (int i = 0; i < 4; ++i) {
    long long off = (long long)(r0 + ty + i * 8) * C + (c0 + tx);
    tile[ty + i * 8][tx] = isb ? inb[off] : f2b(inf[off]);
  }
  __syncthreads();
#pragma unroll
  for (int i = 0; i < 4; ++i)
    out[(long long)(c0 + ty + i * 8) * R + (r0 + tx)] = tile[tx][ty + i * 8];
}

__global__ void rotary_q_kernel(bf16* __restrict__ q, const bf16* __restrict__ srcf) {
  int idx = blockIdx.x * 256 + threadIdx.x;
  int row = idx >> 9;
  int p = idx & 511;
  int h = p >> 5, i = p & 31;
  int d0 = h * 64 + 2 * i;
  int ntok = row & 255;
  float f = b2f(srcf[ntok * 64 + 2 * i]);
  float c = cosf(f), s = sinf(f);
  long long base = (long long)row * 1024 + d0;
  float q0 = b2f(q[base]), q1 = b2f(q[base + 1]);
  q[base]     = f2b(q0 * c - q1 * s);
  q[base + 1] = f2b(q1 * c + q0 * s);
}

__global__ void k_bias_rot_kernel(bf16* __restrict__ k, const bf16* __restrict__ tgtf,
                                  const bf16* __restrict__ rpe,
                                  const int* __restrict__ ridx, int layer) {
  int idx = blockIdx.x * 256 + threadIdx.x;
  int b = idx >> 19;
  int rem = idx & ((1 << 19) - 1);
  int j = rem >> 9;
  int p = rem & 511;
  int h = p >> 5, i = p & 31;
  int d0 = h * 64 + 2 * i;
  float bias = b2f(rpe[(layer * 405 + ridx[j >> 8]) * 16 + h]);
  float f = b2f(tgtf[j * 64 + 2 * i]);
  float c = cosf(f), s = sinf(f);
  long long base = (long long)(b * 1088 + j) * 1024 + d0;
  float k0 = b2f(k[base]) + bias, k1 = b2f(k[base + 1]) + bias;
  k[base]     = f2b(k0 * c - k1 * s);
  k[base + 1] = f2b(k1 * c + k0 * s);
}

__global__ void geglu_kernel(const bf16* __restrict__ hgl, bf16* __restrict__ y) {
  int idx = blockIdx.x * 256 + threadIdx.x;
  int m = idx >> 12, n = idx & 4095;
  float a = b2f(hgl[(long long)m * 8192 + n]);
  float g = b2f(hgl[(long long)m * 8192 + 4096 + n]);
  float ge = 0.5f * g * (1.0f + erff(g * 0.70710678118654752f));
  y[idx] = f2b(a * ge);
}

// ---------------------------------------------------------------------------
extern "C" void kernel_launch(void* const* d_in, const int* in_sizes, int n_in,
                              void* d_out, int out_size, void* d_ws, size_t ws_size,
                              hipStream_t stream) {
  (void)in_sizes; (void)n_in; (void)out_size; (void)ws_size;
  const void* x    = d_in[0];
  const void* cond = d_in[1];
  const void* Wq   = d_in[2];
  const void* Wk   = d_in[3];
  const void* Wv   = d_in[4];
  const void* Wo   = d_in[5];
  const void* bo   = d_in[6];
  const void* rpe  = d_in[7];
  const void* W1   = d_in[8];
  const void* b1   = d_in[9];
  const void* W2   = d_in[10];
  const void* b2   = d_in[11];
  const void* srcf = d_in[12];
  const void* tgtf = d_in[13];
  const int*  ridx = (const int*)d_in[14];

  char* w = (char*)d_ws;
  int* flag = (int*)w;   w += 256;
  bf16* WqT = (bf16*)w;  w += (size_t)2 * 1024 * 1024 * 2;
  bf16* WkT = (bf16*)w;  w += (size_t)2 * 1024 * 1024 * 2;
  bf16* WvT = (bf16*)w;  w += (size_t)2 * 1024 * 1024 * 2;
  bf16* WoT = (bf16*)w;  w += (size_t)2 * 1024 * 1024 * 2;
  bf16* W1T = (bf16*)w;  w += (size_t)2 * 8192 * 1024 * 2;
  bf16* W2T = (bf16*)w;  w += (size_t)2 * 4096 * 1024 * 2;
  bf16* condb = (bf16*)w; w += (size_t)8704 * 1024 * 2;
  bf16* bo_b = (bf16*)w;  w += 2048 * 2;
  bf16* rpe_b = (bf16*)w; w += 12960 * 2;
  bf16* b1_b = (bf16*)w;  w += 16384 * 2;
  bf16* b2_b = (bf16*)w;  w += 2048 * 2;
  bf16* srcf_b = (bf16*)w; w += 16384 * 2;
  bf16* tgtf_b = (bf16*)w; w += 65536 * 2;
  float* xf = (float*)w; w += (size_t)2048 * 1024 * 4;
  bf16* xbf = (bf16*)w;  w += (size_t)2048 * 1024 * 2;
  bf16* qbuf = (bf16*)w; w += (size_t)2048 * 1024 * 2;
  bf16* kbuf = (bf16*)w; w += (size_t)8704 * 1024 * 2;
  bf16* vTf = (bf16*)w;  w += (size_t)1024 * 8704 * 2;
  bf16* att = (bf16*)w;  w += (size_t)2048 * 1024 * 2;
  bf16* hgl = (bf16*)w;  w += (size_t)2048 * 8192 * 2;   // 32 MiB
  bf16* ybuf = (bf16*)w; w += (size_t)2048 * 4096 * 2;   // 16 MiB
  float* pbuf = (float*)hgl;  // split-K partials (4 x 8 MiB) alias dead hgl

  detect_dtype<<<1, 1, 0, stream>>>((const unsigned int*)x, flag);

  convert_in<<<34816, 256, 0, stream>>>(cond, condb, 8704 * 1024, flag);
  convert_in<<<8, 256, 0, stream>>>(bo, bo_b, 2048, flag);
  convert_in<<<51, 256, 0, stream>>>(rpe, rpe_b, 12960, flag);
  convert_in<<<64, 256, 0, stream>>>(b1, b1_b, 16384, flag);
  convert_in<<<8, 256, 0, stream>>>(b2, b2_b, 2048, flag);
  convert_in<<<64, 256, 0, stream>>>(srcf, srcf_b, 16384, flag);
  convert_in<<<256, 256, 0, stream>>>(tgtf, tgtf_b, 65536, flag);

  dim3 tb(32, 8);
  transpose_w<<<dim3(32, 32, 2),  tb, 0, stream>>>(Wq, WqT, 1024, 1024, flag);
  transpose_w<<<dim3(32, 32, 2),  tb, 0, stream>>>(Wk, WkT, 1024, 1024, flag);
  transpose_w<<<dim3(32, 32, 2),  tb, 0, stream>>>(Wv, WvT, 1024, 1024, flag);
  transpose_w<<<dim3(32, 32, 2),  tb, 0, stream>>>(Wo, WoT, 1024, 1024, flag);
  transpose_w<<<dim3(256, 32, 2), tb, 0, stream>>>(W1, W1T, 1024, 8192, flag);
  transpose_w<<<dim3(32, 128, 2), tb, 0, stream>>>(W2, W2T, 4096, 1024, flag);
  init_x_kernel<<<8192, 256, 0, stream>>>(x, flag, xf, xbf);

  for (int l = 0; l < 2; ++l) {
    const bf16* WqTl = WqT + (size_t)l * 1024 * 1024;
    const bf16* WkTl = WkT + (size_t)l * 1024 * 1024;
    const bf16* WvTl = WvT + (size_t)l * 1024 * 1024;
    const bf16* WoTl = WoT + (size_t)l * 1024 * 1024;
    const bf16* W1Tl = W1T + (size_t)l * 8192 * 1024;
    const bf16* W2Tl = W2T + (size_t)l * 4096 * 1024;

    // TAG 0: q = x @ Wq   (M=2048, N=1024)
    gemm_bt<0><<<dim3(8, 16), 256, 0, stream>>>(xbf, 1024, WqTl, 1024, 1.f,
        nullptr, nullptr, nullptr, qbuf, 1024, 1024);
    rotary_q_kernel<<<4096, 256, 0, stream>>>(qbuf, srcf_b);
    // TAG 1: V^T = Wv^T @ cond^T   (M=1024, N=8704)
    gemm_bt<1><<<dim3(68, 8), 256, 0, stream>>>(WvTl, 1024, condb, 1024, 1.f,
        nullptr, nullptr, nullptr, vTf, 8704, 1024);
    // TAG 2: k = cond @ Wk   (M=8704, N=1024)
    gemm_bt<2><<<dim3(8, 68), 256, 0, stream>>>(condb, 1024, WkTl, 1024, 1.f,
        nullptr, nullptr, nullptr, kbuf, 1024, 1024);
    k_bias_rot_kernel<<<16384, 256, 0, stream>>>(kbuf, tgtf_b, rpe_b, ridx, l);
    // fused attention
    flash_attn<<<256, 256, 0, stream>>>(qbuf, kbuf, vTf, att);
    // TAG 3: x = x + O @ Wo + bo   (M=2048, N=1024)
    gemm_bt<3><<<dim3(8, 16), 256, 0, stream>>>(att, 1024, WoTl, 1024, 1.f,
        xf, bo_b + (size_t)l * 1024, xf, xbf, 1024, 1024);
    // TAG 4: FF1 hgl = x @ W1 + b1   (M=2048, N=8192)
    gemm_bt<4><<<dim3(64, 16), 256, 0, stream>>>(xbf, 1024, W1Tl, 1024, 1.f,
        nullptr, b1_b + (size_t)l * 8192, nullptr, hgl, 8192, 1024);
    geglu_kernel<<<32768, 256, 0, stream>>>(hgl, ybuf);
    // FF2 split-K into partials (alias hgl, now dead) + fused reduce
    gemm_splitk<<<dim3(8, 16, 4), 256, 0, stream>>>(ybuf, 4096, W2Tl, 4096,
                                                    pbuf, 1024, 2048, 1024);
    reduce_ff2<<<8192, 256, 0, stream>>>(pbuf, b2_b + (size_t)l * 1024, xf, xbf);
  }

  emit_kernel<<<8192, 256, 0, stream>>>(xf, flag, d_out);
}